// Round 4
// baseline (441.380 us; speedup 1.0000x reference)
//
#include <hip/hip_runtime.h>
#include <hip/hip_fp16.h>

// Graph scaled-dot-product attention, N=50000, E=800000, H=8, D=64.
// seg_sum[n] = Q[n] @ (sum_{e:A_e=n} K[B_e])^T -- only Ksum needed per node.
// k pre-converted to f16 to halve gather bytes.
//
// Round-4 structure: TWO dispatches (round 3 showed ~36-40us fixed cost per
// dispatch; 6 preprocessing dispatches ~272us for ~55us of work).
//   D1: convert k->f16 + scatter edges into fixed-cap slack cells per
//       (edge-block, bucket) with LDS cursors (no scan, no global atomics).
//   D2: node kernel collects its 4 nodes' edges straight from the bucket's
//       slack cells into LDS lists, then runs the verified gather/softmax/PV.
// No cooperative launch (round 2: grid.sync ~700us). No single-block serial
// work (round 1). Node math identical to rounds 1-3 (passed, absmax 0.0156).

#define ROW 512          // H*D floats per node
#define LPAD 68          // padded LDS row stride (floats)
#define EPB 4096         // edges per D1 edge-block (256 thr * 16)
#define CAP 64           // slots per (edge-block, bucket) cell. lambda~21,
                         // P(cell overflow) ~1e-9 -- and guarded by min().
#define DEGCAP 128       // max supported in-degree (lambda=16, P(>128)~1e-80)

typedef float f4 __attribute__((ext_vector_type(4)));
typedef unsigned int u4 __attribute__((ext_vector_type(4)));

// ---------------- f32 -> f16 convert, 8 elems/thread ----------------
__device__ __forceinline__ void dev_convert(const float* __restrict__ k,
                                            unsigned int* __restrict__ kh, int i) {
    const f4* src = (const f4*)k + (size_t)i * 2;
    f4 x0 = __builtin_nontemporal_load(src);       // k f32 read once
    f4 x1 = __builtin_nontemporal_load(src + 1);
    union { __half2 h2; unsigned int u; } c0, c1, c2, c3;
    c0.h2 = __floats2half2_rn(x0.x, x0.y);
    c1.h2 = __floats2half2_rn(x0.z, x0.w);
    c2.h2 = __floats2half2_rn(x1.x, x1.y);
    c3.h2 = __floats2half2_rn(x1.z, x1.w);
    u4 o = {c0.u, c1.u, c2.u, c3.u};
    ((u4*)kh)[i] = o;
}

// ---------------- f16 accumulate helper ----------------
__device__ __forceinline__ void acc8(u4 x, f4& a0, f4& a1) {
    union { unsigned int u; __half2 h; } p0{x.x}, p1{x.y}, p2{x.z}, p3{x.w};
    a0.x += __low2float(p0.h); a0.y += __high2float(p0.h);
    a0.z += __low2float(p1.h); a0.w += __high2float(p1.h);
    a1.x += __low2float(p2.h); a1.y += __high2float(p2.h);
    a1.z += __low2float(p3.h); a1.w += __high2float(p3.h);
}

// ================= D1: convert + slack-cell edge bucketing =================
// blocks [0, HB): edge blocks.  blocks [HB, ...): convert blocks.
__global__ __launch_bounds__(256) void prep_kernel(
    const int* __restrict__ A, const int* __restrict__ Bs,
    int* __restrict__ cnts, int* __restrict__ tmp, int E, int HB, int NB,
    const float* __restrict__ k, unsigned int* __restrict__ kh, int total8)
{
    __shared__ int cur[256];
    int blk = blockIdx.x, t = threadIdx.x;
    if (blk >= HB) {                 // -------- convert part --------
        int i = (blk - HB) * 256 + t;
        if (i < total8) dev_convert(k, kh, i);
        return;
    }
    // -------- edge bucketing part --------
    cur[t] = 0;
    __syncthreads();
    int base = blk * EPB + t * 16;
    bool bal = ((((unsigned long long)(size_t)Bs) & 15) == 0);
    if (base + 16 <= E && bal) {
        #pragma unroll
        for (int c = 0; c < 4; ++c) {
            int4 a = *(const int4*)(A + base + c * 4);
            int4 b = *(const int4*)(Bs + base + c * 4);
            int as[4] = {a.x, a.y, a.z, a.w};
            int bs[4] = {b.x, b.y, b.z, b.w};
            #pragma unroll
            for (int j = 0; j < 4; ++j) {
                int g = as[j] >> 8;
                int pos = atomicAdd(&cur[g], 1);              // LDS atomic
                if (pos < CAP)
                    tmp[((size_t)blk * NB + g) * CAP + pos] = ((as[j] & 255) << 24) | bs[j];
            }
        }
    } else {
        for (int j = 0; j < 16; ++j) {
            int i = base + j;
            if (i < E) {
                int a = A[i], b = Bs[i], g = a >> 8;
                int pos = atomicAdd(&cur[g], 1);
                if (pos < CAP)
                    tmp[((size_t)blk * NB + g) * CAP + pos] = ((a & 255) << 24) | b;
            }
        }
    }
    __syncthreads();
    if (t < NB) cnts[blk * NB + t] = (cur[t] < CAP) ? cur[t] : CAP;
}

// ================= D2: collect edges from cells + node attention =================
__global__ __launch_bounds__(256) void node16s(
    const float* __restrict__ q, const unsigned int* __restrict__ kh,
    const float* __restrict__ v, const int* __restrict__ cnts,
    const int* __restrict__ tmp, float* __restrict__ out, int N, int HB, int NB)
{
    __shared__ float lds[4][2 * 8 * LPAD + 64 + 8];
    __shared__ int slist[4][DEGCAP];
    __shared__ int scnt[4];
    int t = threadIdx.x, lane = t & 63, wid = t >> 6;
    int n0 = blockIdx.x * 4;
    int n  = n0 + wid;
    int g  = n0 >> 8;                 // all 4 nodes share one bucket (4 | 256)
    int r0 = n0 & 255;
    bool active = n < N;

    float* qs = &lds[wid][0];
    float* ks = qs + 8 * LPAD;
    float* ps = ks + 8 * LPAD;

    if (t < 4) scnt[t] = 0;
    __syncthreads();

    // ---- collection: thread t scans cell (b=t[,+256..], g) for our 4 nodes
    for (int b = t; b < HB; b += 256) {
        int c = cnts[b * NB + g];
        const int4* cell = (const int4*)(tmp + ((size_t)b * NB + g) * CAP);
        for (int s = 0; s < c; s += 4) {
            int4 w4 = cell[s >> 2];                 // slots beyond c are garbage,
            int ws[4] = {w4.x, w4.y, w4.z, w4.w};   // masked below
            #pragma unroll
            for (int j = 0; j < 4; ++j) {
                if (s + j < c) {
                    unsigned d = (((unsigned)ws[j] >> 24) & 255u) - (unsigned)r0;
                    if (d < 4u) {
                        int p = atomicAdd(&scnt[d], 1);
                        if (p < DEGCAP) slist[d][p] = ws[j] & 0xFFFFFF;
                    }
                }
            }
        }
    }

    // ---- stage q (independent of collection; hides under it)
    if (active) {
        int r = lane >> 4;
        int dq = (lane & 15) * 4;
        const f4* qn = (const f4*)(q + (size_t)n * ROW);
        f4 q0 = __builtin_nontemporal_load(qn + lane);
        f4 q1 = __builtin_nontemporal_load(qn + 64 + lane);
        *(f4*)(qs + r * LPAD + dq)       = q0;
        *(f4*)(qs + (r + 4) * LPAD + dq) = q1;
    }
    __syncthreads();

    int deg = scnt[wid];
    if (deg > DEGCAP) deg = DEGCAP;
    const int* sl = slist[wid];

    // ---- Ksum gather from LDS source list
    const u4* kh4 = (const u4*)kh;   // one u4 = 8 halves; one row = 64 u4
    f4 a0 = {0.f, 0.f, 0.f, 0.f}, a1 = {0.f, 0.f, 0.f, 0.f};
    int e = 0;
    for (; e + 8 <= deg; e += 8) {   // 8 independent 16B loads in flight
        int b0 = sl[e],     b1 = sl[e + 1], b2 = sl[e + 2], b3 = sl[e + 3];
        int b4 = sl[e + 4], b5 = sl[e + 5], b6 = sl[e + 6], b7 = sl[e + 7];
        u4 x0 = kh4[(size_t)b0 * 64 + lane];
        u4 x1 = kh4[(size_t)b1 * 64 + lane];
        u4 x2 = kh4[(size_t)b2 * 64 + lane];
        u4 x3 = kh4[(size_t)b3 * 64 + lane];
        u4 x4 = kh4[(size_t)b4 * 64 + lane];
        u4 x5 = kh4[(size_t)b5 * 64 + lane];
        u4 x6 = kh4[(size_t)b6 * 64 + lane];
        u4 x7 = kh4[(size_t)b7 * 64 + lane];
        acc8(x0, a0, a1); acc8(x1, a0, a1); acc8(x2, a0, a1); acc8(x3, a0, a1);
        acc8(x4, a0, a1); acc8(x5, a0, a1); acc8(x6, a0, a1); acc8(x7, a0, a1);
    }
    for (; e + 4 <= deg; e += 4) {
        int b0 = sl[e], b1 = sl[e + 1], b2 = sl[e + 2], b3 = sl[e + 3];
        u4 x0 = kh4[(size_t)b0 * 64 + lane];
        u4 x1 = kh4[(size_t)b1 * 64 + lane];
        u4 x2 = kh4[(size_t)b2 * 64 + lane];
        u4 x3 = kh4[(size_t)b3 * 64 + lane];
        acc8(x0, a0, a1); acc8(x1, a0, a1); acc8(x2, a0, a1); acc8(x3, a0, a1);
    }
    for (; e < deg; ++e) {
        u4 x = kh4[(size_t)sl[e] * 64 + lane];
        acc8(x, a0, a1);
    }

    if (active) {
        // lane holds Ksum flat elems [lane*8, lane*8+8): row g = lane>>3, d=(lane&7)*8+j
        int gg = lane >> 3;
        int dbase = (lane & 7) * 8;
        *(f4*)(ks + gg * LPAD + dbase)     = a0;
        *(f4*)(ks + gg * LPAD + dbase + 4) = a1;
    }
    __syncthreads();

    if (active) {
        int h = lane >> 3, gg = lane & 7;
        const f4* qrow = (const f4*)(qs + h * LPAD);
        const f4* krow = (const f4*)(ks + gg * LPAD);
        float acc = 0.f;
        #pragma unroll
        for (int i = 0; i < 16; ++i) {
            f4 qa = qrow[i];
            f4 kb = krow[i];
            acc += qa.x * kb.x + qa.y * kb.y + qa.z * kb.z + qa.w * kb.w;
        }
        float score = acc / (float)((deg > 0) ? deg : 1);
        float mx = score;
        #pragma unroll
        for (int off = 1; off < 8; off <<= 1)
            mx = fmaxf(mx, __shfl_xor(mx, off, 8));
        float ex = __expf(score - mx);
        float sm = ex;
        #pragma unroll
        for (int off = 1; off < 8; off <<= 1)
            sm += __shfl_xor(sm, off, 8);
        ps[h * 8 + gg] = ex / sm;
    }
    __syncthreads();

    if (active) {
        int h0 = lane >> 4;
        int dbase = (lane & 15) * 4;
        const float* vb = v + (size_t)n * ROW;
        f4 o0 = {0.f, 0.f, 0.f, 0.f}, o1 = {0.f, 0.f, 0.f, 0.f};
        #pragma unroll
        for (int gg = 0; gg < 8; ++gg) {
            f4 vg = __builtin_nontemporal_load((const f4*)(vb + gg * 64 + dbase));
            float p0 = ps[h0 * 8 + gg];
            float p1 = ps[(h0 + 4) * 8 + gg];
            o0 += p0 * vg;
            o1 += p1 * vg;
        }
        f4* ob = (f4*)(out + (size_t)n * ROW);
        __builtin_nontemporal_store(o0, ob + lane);
        __builtin_nontemporal_store(o1, ob + 64 + lane);
    }
}

// ================= D2 fallback: f32 k (workspace too small for kh) =================
__global__ __launch_bounds__(256) void node32s(
    const float* __restrict__ q, const float* __restrict__ k,
    const float* __restrict__ v, const int* __restrict__ cnts,
    const int* __restrict__ tmp, float* __restrict__ out, int N, int HB, int NB)
{
    __shared__ float lds[4][2 * 8 * LPAD + 64 + 8];
    __shared__ int slist[4][DEGCAP];
    __shared__ int scnt[4];
    int t = threadIdx.x, lane = t & 63, wid = t >> 6;
    int n0 = blockIdx.x * 4;
    int n  = n0 + wid;
    int g  = n0 >> 8;
    int r0 = n0 & 255;
    bool active = n < N;

    float* qs = &lds[wid][0];
    float* ks = qs + 8 * LPAD;
    float* ps = ks + 8 * LPAD;

    if (t < 4) scnt[t] = 0;
    __syncthreads();

    for (int b = t; b < HB; b += 256) {
        int c = cnts[b * NB + g];
        const int4* cell = (const int4*)(tmp + ((size_t)b * NB + g) * CAP);
        for (int s = 0; s < c; s += 4) {
            int4 w4 = cell[s >> 2];
            int ws[4] = {w4.x, w4.y, w4.z, w4.w};
            #pragma unroll
            for (int j = 0; j < 4; ++j) {
                if (s + j < c) {
                    unsigned d = (((unsigned)ws[j] >> 24) & 255u) - (unsigned)r0;
                    if (d < 4u) {
                        int p = atomicAdd(&scnt[d], 1);
                        if (p < DEGCAP) slist[d][p] = ws[j] & 0xFFFFFF;
                    }
                }
            }
        }
    }

    if (active) {
        int r = lane >> 4;
        int dq = (lane & 15) * 4;
        const f4* qn = (const f4*)(q + (size_t)n * ROW);
        f4 q0 = qn[lane], q1 = qn[64 + lane];
        *(f4*)(qs + r * LPAD + dq)       = q0;
        *(f4*)(qs + (r + 4) * LPAD + dq) = q1;
    }
    __syncthreads();

    int deg = scnt[wid];
    if (deg > DEGCAP) deg = DEGCAP;
    const int* sl = slist[wid];

    f4 a0 = {0.f, 0.f, 0.f, 0.f}, a1 = {0.f, 0.f, 0.f, 0.f};
    for (int e = 0; e < deg; ++e) {
        int b = sl[e];
        const f4* kb = (const f4*)(k + (size_t)b * ROW);
        f4 x0 = kb[lane];
        f4 x1 = kb[64 + lane];
        a0 += x0; a1 += x1;
    }

    if (active) {
        int gg = lane >> 3;
        int dbase = (lane & 7) * 8;
        *(f4*)(ks + gg * LPAD + dbase)     = a0;
        *(f4*)(ks + gg * LPAD + dbase + 4) = a1;
    }
    __syncthreads();

    if (active) {
        int h = lane >> 3, gg = lane & 7;
        const f4* qrow = (const f4*)(qs + h * LPAD);
        const f4* krow = (const f4*)(ks + gg * LPAD);
        float acc = 0.f;
        #pragma unroll
        for (int i = 0; i < 16; ++i) {
            f4 qa = qrow[i];
            f4 kb = krow[i];
            acc += qa.x * kb.x + qa.y * kb.y + qa.z * kb.z + qa.w * kb.w;
        }
        float score = acc / (float)((deg > 0) ? deg : 1);
        float mx = score;
        #pragma unroll
        for (int off = 1; off < 8; off <<= 1)
            mx = fmaxf(mx, __shfl_xor(mx, off, 8));
        float ex = __expf(score - mx);
        float sm = ex;
        #pragma unroll
        for (int off = 1; off < 8; off <<= 1)
            sm += __shfl_xor(sm, off, 8);
        ps[h * 8 + gg] = ex / sm;
    }
    __syncthreads();

    if (active) {
        int h0 = lane >> 4;
        int dbase = (lane & 15) * 4;
        const float* vb = v + (size_t)n * ROW;
        f4 o0 = {0.f, 0.f, 0.f, 0.f}, o1 = {0.f, 0.f, 0.f, 0.f};
        #pragma unroll
        for (int gg = 0; gg < 8; ++gg) {
            f4 vg = *(const f4*)(vb + gg * 64 + dbase);
            float p0 = ps[h0 * 8 + gg];
            float p1 = ps[(h0 + 4) * 8 + gg];
            o0 += p0 * vg;
            o1 += p1 * vg;
        }
        f4* ob = (f4*)(out + (size_t)n * ROW);
        ob[lane]      = o0;
        ob[64 + lane] = o1;
    }
}

// ================= host launcher =================
extern "C" void kernel_launch(void* const* d_in, const int* in_sizes, int n_in,
                              void* d_out, int out_size, void* d_ws, size_t ws_size,
                              hipStream_t stream) {
    const float* q  = (const float*)d_in[0];
    const float* k  = (const float*)d_in[1];
    const float* v  = (const float*)d_in[2];
    const int*   ei = (const int*)d_in[3];

    int N = in_sizes[0] / ROW;
    int E = in_sizes[3] / 2;
    const int* A  = ei;
    const int* Bs = ei + E;

    int HB = (E + EPB - 1) / EPB;       // edge blocks (196)
    int NB = (N + 255) >> 8;            // node buckets (196) -- requires N <= 65536

    // workspace: cnts[HB*NB] | tmp[HB*NB*CAP] | kh (f16 k), 256B-aligned
    int* cnts = (int*)d_ws;
    int* tmp  = cnts + (size_t)HB * NB;
    size_t int_words = (size_t)HB * NB * (1 + CAP);
    size_t kh_off = ((int_words * 4 + 255) & ~(size_t)255);
    unsigned int* kh = (unsigned int*)((char*)d_ws + kh_off);
    bool use_f16 = ws_size >= kh_off + (size_t)N * ROW * 2;
    int total8 = N * (ROW / 8);
    int CONVB  = (total8 + 255) / 256;
    float* out = (float*)d_out;

    prep_kernel<<<HB + (use_f16 ? CONVB : 0), 256, 0, stream>>>(
        A, Bs, cnts, tmp, E, HB, NB, k, kh, total8);
    if (use_f16)
        node16s<<<(N + 3) / 4, 256, 0, stream>>>(q, kh, v, cnts, tmp, out, N, HB, NB);
    else
        node32s<<<(N + 3) / 4, 256, 0, stream>>>(q, k, v, cnts, tmp, out, N, HB, NB);
}

// Round 5
// 431.539 us; speedup vs baseline: 1.0228x; 1.0228x over previous
//
#include <hip/hip_runtime.h>
#include <hip/hip_fp16.h>

// Graph scaled-dot-product attention, N=50000, E=800000, H=8, D=64.
// seg_sum[n] = Q[n] @ (sum_{e:A_e=n} K[B_e])^T -- only Ksum needed per node.
// k pre-converted to f16 to halve gather bytes.
//
// Round-5: round-3 structure (best node kernel, 151us) with ONE change:
// the k->f16 convert no longer uses nontemporal loads, and runs as its own
// dispatch. Theory: NT path throttled the 150MB convert to ~1TB/s (~180us,
// the hidden cost in every round) and evicted kh from L2/L3 before the
// node gather. Plain loads -> convert ~30us and kh stays cache-resident.
// Dispatch overhead measured ~5us (R3->R4: -5 dispatches = -26us), so the
// 8-dispatch structure is fine. Node kernel byte-identical to round 3.

#define ROW 512          // H*D floats per node
#define LPAD 68          // padded LDS row stride (floats)
#define EPB 2048         // edges per hist/scatter chunk (256 thr * 8)

typedef float f4 __attribute__((ext_vector_type(4)));
typedef unsigned int u4 __attribute__((ext_vector_type(4)));

// ================= device helpers =================

// block-wide exclusive scan over 256 ints (needs scr[4]+)
__device__ __forceinline__ int excl_scan_256(int x, int t, int* scr) {
    int lane = t & 63, w = t >> 6;
    int v = x;
    #pragma unroll
    for (int off = 1; off < 64; off <<= 1) {
        int u = __shfl_up(v, off, 64);
        if (lane >= off) v += u;
    }
    __syncthreads();
    if (lane == 63) scr[w] = v;
    __syncthreads();
    int base = 0;
    #pragma unroll
    for (int i = 0; i < 4; ++i) if (i < w) base += scr[i];
    return base + v - x;             // exclusive prefix
}

// ---------------- f16 accumulate helper ----------------
__device__ __forceinline__ void acc8(u4 x, f4& a0, f4& a1) {
    union { unsigned int u; __half2 h; } p0{x.x}, p1{x.y}, p2{x.z}, p3{x.w};
    a0.x += __low2float(p0.h); a0.y += __high2float(p0.h);
    a0.z += __low2float(p1.h); a0.w += __high2float(p1.h);
    a1.x += __low2float(p2.h); a1.y += __high2float(p2.h);
    a1.z += __low2float(p3.h); a1.w += __high2float(p3.h);
}

// ================= dispatch kernels =================

// ---- 0. convert k -> f16, PLAIN loads/stores (kh stays L2/L3-resident)
__global__ __launch_bounds__(256) void w_convert(
    const float* __restrict__ k, unsigned int* __restrict__ kh, int total8)
{
    int i = blockIdx.x * 256 + threadIdx.x;
    if (i >= total8) return;
    const f4* src = (const f4*)k + (size_t)i * 2;
    f4 x0 = src[0];
    f4 x1 = src[1];
    union { __half2 h2; unsigned int u; } c0, c1, c2, c3;
    c0.h2 = __floats2half2_rn(x0.x, x0.y);
    c1.h2 = __floats2half2_rn(x0.z, x0.w);
    c2.h2 = __floats2half2_rn(x1.x, x1.y);
    c3.h2 = __floats2half2_rn(x1.z, x1.w);
    u4 o = {c0.u, c1.u, c2.u, c3.u};
    ((u4*)kh)[i] = o;
}

// ---- 1. per-chunk bucket histogram
__global__ __launch_bounds__(256) void w_hist(
    const int* __restrict__ A, int* __restrict__ bh, int E, int HB, int NB)
{
    __shared__ int h[256];
    int blk = blockIdx.x, t = threadIdx.x;
    h[t] = 0;
    __syncthreads();
    int base = blk * EPB + t * 8;
    if (base + 8 <= E) {
        int4 a0 = *(const int4*)(A + base);
        int4 a1 = *(const int4*)(A + base + 4);
        atomicAdd(&h[a0.x >> 8], 1); atomicAdd(&h[a0.y >> 8], 1);
        atomicAdd(&h[a0.z >> 8], 1); atomicAdd(&h[a0.w >> 8], 1);
        atomicAdd(&h[a1.x >> 8], 1); atomicAdd(&h[a1.y >> 8], 1);
        atomicAdd(&h[a1.z >> 8], 1); atomicAdd(&h[a1.w >> 8], 1);
    } else {
        for (int j = 0; j < 8; ++j) { int i = base + j; if (i < E) atomicAdd(&h[A[i] >> 8], 1); }
    }
    __syncthreads();
    if (t < NB) bh[t * HB + blk] = h[t];   // bucket-major matrix
}

// ---- 2. per-bucket row sums (one block per bucket)
__global__ __launch_bounds__(256) void w_rowsum(const int* __restrict__ bh,
                                                int* __restrict__ rowsum, int HB) {
    __shared__ int scr[4];
    int g = blockIdx.x, t = threadIdx.x;
    int s = 0;
    for (int c = t; c < HB; c += 256) s += bh[g * HB + c];
    #pragma unroll
    for (int off = 32; off; off >>= 1) s += __shfl_down(s, off, 64);
    int lane = t & 63, w = t >> 6;
    if (lane == 0) scr[w] = s;
    __syncthreads();
    if (t == 0) rowsum[g] = scr[0] + scr[1] + scr[2] + scr[3];
}

// ---- 3. scan bucket bases (one tiny block over NB<=256 ints)
__global__ __launch_bounds__(256) void w_scanbase(const int* __restrict__ rowsum,
                                                  int* __restrict__ rowbase,
                                                  int* __restrict__ offsets,
                                                  int NB, int N, int E) {
    __shared__ int scr[4];
    int t = threadIdx.x;
    int x = (t < NB) ? rowsum[t] : 0;
    int p = excl_scan_256(x, t, scr);
    if (t <= NB) rowbase[t] = p;     // rowbase[NB] == E
    if (t == 0) offsets[N] = E;
}

// ---- 4. exclusive scan along each bucket row (one block per bucket)
__global__ __launch_bounds__(256) void w_rowscan(int* __restrict__ bh,
                                                 const int* __restrict__ rowbase, int HB) {
    __shared__ int scr[4];
    int g = blockIdx.x, t = threadIdx.x;
    int j0 = 2 * t, j1 = 2 * t + 1;
    int c0 = (j0 < HB) ? bh[g * HB + j0] : 0;
    int c1 = (j1 < HB) ? bh[g * HB + j1] : 0;
    int p = excl_scan_256(c0 + c1, t, scr);
    int base = rowbase[g];
    if (j0 < HB) bh[g * HB + j0] = base + p;
    if (j1 < HB) bh[g * HB + j1] = base + p + c0;
}

// ---- 5. scatter edges into bucket order (LDS cursors, no global atomics)
__global__ __launch_bounds__(256) void w_scatter(
    const int* __restrict__ A, const int* __restrict__ Bs, const int* __restrict__ bh,
    int* __restrict__ tmp, int E, int HB, int NB)
{
    __shared__ int cur[256];
    int blk = blockIdx.x, t = threadIdx.x;
    if (t < NB) cur[t] = bh[t * HB + blk];
    __syncthreads();
    int base = blk * EPB + t * 8;
    bool bal = ((((unsigned long long)(size_t)Bs) & 15) == 0);
    if (base + 8 <= E && bal) {
        int4 a0 = *(const int4*)(A + base);
        int4 a1 = *(const int4*)(A + base + 4);
        int4 b0 = *(const int4*)(Bs + base);
        int4 b1 = *(const int4*)(Bs + base + 4);
        int as[8] = {a0.x, a0.y, a0.z, a0.w, a1.x, a1.y, a1.z, a1.w};
        int bs[8] = {b0.x, b0.y, b0.z, b0.w, b1.x, b1.y, b1.z, b1.w};
        #pragma unroll
        for (int j = 0; j < 8; ++j) {
            int pos = atomicAdd(&cur[as[j] >> 8], 1);      // LDS atomic
            tmp[pos] = ((as[j] & 255) << 24) | bs[j];      // pack (A&255, B)
        }
    } else {
        for (int j = 0; j < 8; ++j) {
            int i = base + j;
            if (i < E) {
                int a = A[i], b = Bs[i];
                int pos = atomicAdd(&cur[a >> 8], 1);
                tmp[pos] = ((a & 255) << 24) | b;
            }
        }
    }
}

// ---- 6. per-bucket offsets + srcs (owner-computes, one block per bucket)
__global__ __launch_bounds__(256) void w_build(
    const int* __restrict__ rowbase, const int* __restrict__ tmp,
    int* __restrict__ offsets, int* __restrict__ srcs, int N, int E, int NB)
{
    __shared__ int cnt[256];
    __shared__ int scr[4];
    int g = blockIdx.x, t = threadIdx.x;
    int s = rowbase[g];
    int e = rowbase[g + 1];
    cnt[t] = 0;
    __syncthreads();
    for (int i = s + t; i < e; i += 256) atomicAdd(&cnt[(tmp[i] >> 24) & 255], 1);
    __syncthreads();
    int val = cnt[t];
    int p = excl_scan_256(val, t, scr);
    int n0 = (g << 8) + t;
    if (n0 < N) offsets[n0] = s + p;
    __syncthreads();
    cnt[t] = s + p;                  // reuse as cursor
    __syncthreads();
    for (int i = s + t; i < e; i += 256) {
        int wv = tmp[i];
        int pos = atomicAdd(&cnt[(wv >> 24) & 255], 1);   // LDS atomic
        srcs[pos] = wv & 0xFFFFFF;
    }
}

// ---- 7. node attention, f16 k (one wave per node) -- byte-identical to R3
__global__ __launch_bounds__(256) void w_node16(
    const float* __restrict__ q, const unsigned int* __restrict__ kh,
    const float* __restrict__ v, const int* __restrict__ offsets,
    const int* __restrict__ srcs, float* __restrict__ out, int N)
{
    __shared__ float lds[4][2 * 8 * LPAD + 64 + 8];
    int lane = threadIdx.x & 63;
    int wid  = threadIdx.x >> 6;
    int n = blockIdx.x * 4 + wid;
    bool active = n < N;

    float* qs = &lds[wid][0];
    float* ks = qs + 8 * LPAD;
    float* ps = ks + 8 * LPAD;

    int start = 0, end = 0;
    if (active) {
        start = __builtin_amdgcn_readfirstlane(offsets[n]);
        end   = __builtin_amdgcn_readfirstlane(offsets[n + 1]);
        int r0 = lane >> 4;
        int dq = (lane & 15) * 4;
        const f4* qn = (const f4*)(q + (size_t)n * ROW);
        f4 q0 = __builtin_nontemporal_load(qn + lane);
        f4 q1 = __builtin_nontemporal_load(qn + 64 + lane);
        *(f4*)(qs + r0 * LPAD + dq)       = q0;
        *(f4*)(qs + (r0 + 4) * LPAD + dq) = q1;
    }

    const u4* kh4 = (const u4*)kh;   // one u4 = 8 halves; one row = 64 u4
    f4 a0 = {0.f, 0.f, 0.f, 0.f}, a1 = {0.f, 0.f, 0.f, 0.f};
    int e = start;
    for (; e + 8 <= end; e += 8) {   // 8 independent 16B loads in flight
        int b0 = srcs[e],     b1 = srcs[e + 1], b2 = srcs[e + 2], b3 = srcs[e + 3];
        int b4 = srcs[e + 4], b5 = srcs[e + 5], b6 = srcs[e + 6], b7 = srcs[e + 7];
        u4 x0 = kh4[(size_t)b0 * 64 + lane];
        u4 x1 = kh4[(size_t)b1 * 64 + lane];
        u4 x2 = kh4[(size_t)b2 * 64 + lane];
        u4 x3 = kh4[(size_t)b3 * 64 + lane];
        u4 x4 = kh4[(size_t)b4 * 64 + lane];
        u4 x5 = kh4[(size_t)b5 * 64 + lane];
        u4 x6 = kh4[(size_t)b6 * 64 + lane];
        u4 x7 = kh4[(size_t)b7 * 64 + lane];
        acc8(x0, a0, a1); acc8(x1, a0, a1); acc8(x2, a0, a1); acc8(x3, a0, a1);
        acc8(x4, a0, a1); acc8(x5, a0, a1); acc8(x6, a0, a1); acc8(x7, a0, a1);
    }
    for (; e + 4 <= end; e += 4) {
        int b0 = srcs[e], b1 = srcs[e + 1], b2 = srcs[e + 2], b3 = srcs[e + 3];
        u4 x0 = kh4[(size_t)b0 * 64 + lane];
        u4 x1 = kh4[(size_t)b1 * 64 + lane];
        u4 x2 = kh4[(size_t)b2 * 64 + lane];
        u4 x3 = kh4[(size_t)b3 * 64 + lane];
        acc8(x0, a0, a1); acc8(x1, a0, a1); acc8(x2, a0, a1); acc8(x3, a0, a1);
    }
    for (; e < end; ++e) {
        u4 x = kh4[(size_t)srcs[e] * 64 + lane];
        acc8(x, a0, a1);
    }

    if (active) {
        // lane holds Ksum flat elems [lane*8, lane*8+8): row g = lane>>3, d=(lane&7)*8+j
        int g = lane >> 3;
        int dbase = (lane & 7) * 8;
        *(f4*)(ks + g * LPAD + dbase)     = a0;
        *(f4*)(ks + g * LPAD + dbase + 4) = a1;
    }
    __syncthreads();

    if (active) {
        int h = lane >> 3, g = lane & 7;
        const f4* qrow = (const f4*)(qs + h * LPAD);
        const f4* krow = (const f4*)(ks + g * LPAD);
        float acc = 0.f;
        #pragma unroll
        for (int i = 0; i < 16; ++i) {
            f4 qa = qrow[i];
            f4 kb = krow[i];
            acc += qa.x * kb.x + qa.y * kb.y + qa.z * kb.z + qa.w * kb.w;
        }
        int cnt = end - start;
        float score = acc / (float)((cnt > 0) ? cnt : 1);
        float mx = score;
        #pragma unroll
        for (int off = 1; off < 8; off <<= 1)
            mx = fmaxf(mx, __shfl_xor(mx, off, 8));
        float ex = __expf(score - mx);
        float sm = ex;
        #pragma unroll
        for (int off = 1; off < 8; off <<= 1)
            sm += __shfl_xor(sm, off, 8);
        ps[h * 8 + g] = ex / sm;
    }
    __syncthreads();

    if (active) {
        int h0 = lane >> 4;
        int dbase = (lane & 15) * 4;
        const float* vb = v + (size_t)n * ROW;
        f4 o0 = {0.f, 0.f, 0.f, 0.f}, o1 = {0.f, 0.f, 0.f, 0.f};
        #pragma unroll
        for (int g = 0; g < 8; ++g) {
            f4 vg = __builtin_nontemporal_load((const f4*)(vb + g * 64 + dbase));
            float p0 = ps[h0 * 8 + g];
            float p1 = ps[(h0 + 4) * 8 + g];
            o0 += p0 * vg;
            o1 += p1 * vg;
        }
        f4* ob = (f4*)(out + (size_t)n * ROW);
        __builtin_nontemporal_store(o0, ob + lane);
        __builtin_nontemporal_store(o1, ob + 64 + lane);
    }
}

// ---- 7'. node attention, f32 k (fallback if workspace too small)
__global__ __launch_bounds__(256) void w_node32(
    const float* __restrict__ q, const float* __restrict__ k,
    const float* __restrict__ v, const int* __restrict__ offsets,
    const int* __restrict__ srcs, float* __restrict__ out, int N)
{
    __shared__ float lds[4][2 * 8 * LPAD + 64 + 8];
    int lane = threadIdx.x & 63;
    int wid  = threadIdx.x >> 6;
    int n = blockIdx.x * 4 + wid;
    bool active = n < N;

    float* qs = &lds[wid][0];
    float* ks = qs + 8 * LPAD;
    float* ps = ks + 8 * LPAD;

    int start = 0, end = 0;
    if (active) { start = offsets[n]; end = offsets[n + 1]; }

    f4 a0 = {0.f, 0.f, 0.f, 0.f}, a1 = {0.f, 0.f, 0.f, 0.f};
    for (int e = start; e < end; ++e) {
        int b = srcs[e];
        const f4* kb = (const f4*)(k + (size_t)b * ROW);
        f4 x0 = kb[lane];
        f4 x1 = kb[64 + lane];
        a0 += x0; a1 += x1;
    }

    if (active) {
        int r0 = lane >> 4;
        int dbase = (lane & 15) * 4;
        *(f4*)(ks + r0 * LPAD + dbase)       = a0;
        *(f4*)(ks + (r0 + 4) * LPAD + dbase) = a1;
        const f4* qn = (const f4*)(q + (size_t)n * ROW);
        f4 q0 = qn[lane], q1 = qn[64 + lane];
        *(f4*)(qs + r0 * LPAD + dbase)       = q0;
        *(f4*)(qs + (r0 + 4) * LPAD + dbase) = q1;
    }
    __syncthreads();

    if (active) {
        int h = lane >> 3, g = lane & 7;
        const f4* qrow = (const f4*)(qs + h * LPAD);
        const f4* krow = (const f4*)(ks + g * LPAD);
        float acc = 0.f;
        #pragma unroll
        for (int i = 0; i < 16; ++i) {
            f4 qa = qrow[i];
            f4 kb = krow[i];
            acc += qa.x * kb.x + qa.y * kb.y + qa.z * kb.z + qa.w * kb.w;
        }
        int cnt = end - start;
        float score = acc / (float)((cnt > 0) ? cnt : 1);
        float mx = score;
        #pragma unroll
        for (int off = 1; off < 8; off <<= 1)
            mx = fmaxf(mx, __shfl_xor(mx, off, 8));
        float ex = __expf(score - mx);
        float sm = ex;
        #pragma unroll
        for (int off = 1; off < 8; off <<= 1)
            sm += __shfl_xor(sm, off, 8);
        ps[h * 8 + g] = ex / sm;
    }
    __syncthreads();

    if (active) {
        int h0 = lane >> 4;
        int dbase = (lane & 15) * 4;
        const float* vb = v + (size_t)n * ROW;
        f4 o0 = {0.f, 0.f, 0.f, 0.f}, o1 = {0.f, 0.f, 0.f, 0.f};
        #pragma unroll
        for (int g = 0; g < 8; ++g) {
            f4 vg = *(const f4*)(vb + g * 64 + dbase);
            float p0 = ps[h0 * 8 + g];
            float p1 = ps[(h0 + 4) * 8 + g];
            o0 += p0 * vg;
            o1 += p1 * vg;
        }
        f4* ob = (f4*)(out + (size_t)n * ROW);
        ob[lane]      = o0;
        ob[64 + lane] = o1;
    }
}

// ================= host launcher =================
extern "C" void kernel_launch(void* const* d_in, const int* in_sizes, int n_in,
                              void* d_out, int out_size, void* d_ws, size_t ws_size,
                              hipStream_t stream) {
    const float* q  = (const float*)d_in[0];
    const float* k  = (const float*)d_in[1];
    const float* v  = (const float*)d_in[2];
    const int*   ei = (const int*)d_in[3];

    int N = in_sizes[0] / ROW;
    int E = in_sizes[3] / 2;
    const int* A  = ei;
    const int* Bs = ei + E;

    int HB = (E + EPB - 1) / EPB;       // edge chunks (391)
    int NB = (N + 255) >> 8;            // node buckets (196) -- requires N <= 65536

    // workspace layout (ints), then kh (f16 k) 256B-aligned
    int* offsets = (int*)d_ws;                       // N+1
    int* srcs    = offsets + (N + 1);                // E
    int* tmp     = srcs + E;                         // E
    int* bh      = tmp + E;                          // NB*HB
    int* rowsum  = bh + (size_t)NB * HB;             // NB
    int* rowbase = rowsum + NB;                      // NB+1
    size_t int_words = (size_t)(N + 1) + 2 * (size_t)E + (size_t)NB * HB + NB + (NB + 1);
    size_t kh_off = ((int_words * 4 + 255) & ~(size_t)255);
    unsigned int* kh = (unsigned int*)((char*)d_ws + kh_off);
    bool use_f16 = ws_size >= kh_off + (size_t)N * ROW * 2;
    int total8 = N * (ROW / 8);
    int CONVB  = (total8 + 255) / 256;
    float* out = (float*)d_out;

    if (use_f16)
        w_convert<<<CONVB, 256, 0, stream>>>(k, kh, total8);
    w_hist<<<HB, 256, 0, stream>>>(A, bh, E, HB, NB);
    w_rowsum<<<NB, 256, 0, stream>>>(bh, rowsum, HB);
    w_scanbase<<<1, 256, 0, stream>>>(rowsum, rowbase, offsets, NB, N, E);
    w_rowscan<<<NB, 256, 0, stream>>>(bh, rowbase, HB);
    w_scatter<<<HB, 256, 0, stream>>>(A, Bs, bh, tmp, E, HB, NB);
    w_build<<<NB, 256, 0, stream>>>(rowbase, tmp, offsets, srcs, N, E, NB);
    if (use_f16)
        w_node16<<<(N + 3) / 4, 256, 0, stream>>>(q, kh, v, offsets, srcs, out, N);
    else
        w_node32<<<(N + 3) / 4, 256, 0, stream>>>(q, k, v, offsets, srcs, out, N);
}

// Round 6
// 425.823 us; speedup vs baseline: 1.0365x; 1.0134x over previous
//
#include <hip/hip_runtime.h>
#include <hip/hip_fp16.h>

// Graph scaled-dot-product attention, N=50000, E=800000, H=8, D=64.
// seg_sum[n] = Q[n] @ (sum_{e:A_e=n} K[B_e])^T -- only Ksum needed per node.
// k pre-converted to f16 to halve gather bytes.
//
// Round-6: round-3 structure verbatim (422.6us, best measured) + ONE change:
// the node gather software-pipelines the srcs index loads (next group's 8
// indices issued while current group's 8 k-row loads are in flight). Theory:
// node kernel is latency-bound (48% HBM, 29% VALU, nothing saturated); the
// per-group critical path is srcs-load -> k-load two serial hops; prefetching
// the indices removes the first hop. Fixed harness cost ~200us/iteration is
// outside kernel control (cross-round ledger R0/R3/R4/R5 all close on it).

#define ROW 512          // H*D floats per node
#define LPAD 68          // padded LDS row stride (floats)
#define EPB 2048         // edges per hist/scatter chunk (256 thr * 8)

typedef float f4 __attribute__((ext_vector_type(4)));
typedef unsigned int u4 __attribute__((ext_vector_type(4)));

// ================= device helpers =================

__device__ __forceinline__ void dev_convert(const float* __restrict__ k,
                                            unsigned int* __restrict__ kh, int i) {
    const f4* src = (const f4*)k + (size_t)i * 2;
    f4 x0 = __builtin_nontemporal_load(src);       // k f32 read once
    f4 x1 = __builtin_nontemporal_load(src + 1);
    union { __half2 h2; unsigned int u; } c0, c1, c2, c3;
    c0.h2 = __floats2half2_rn(x0.x, x0.y);
    c1.h2 = __floats2half2_rn(x0.z, x0.w);
    c2.h2 = __floats2half2_rn(x1.x, x1.y);
    c3.h2 = __floats2half2_rn(x1.z, x1.w);
    u4 o = {c0.u, c1.u, c2.u, c3.u};
    ((u4*)kh)[i] = o;
}

// block-wide exclusive scan over 256 ints (needs scr[4]+)
__device__ __forceinline__ int excl_scan_256(int x, int t, int* scr) {
    int lane = t & 63, w = t >> 6;
    int v = x;
    #pragma unroll
    for (int off = 1; off < 64; off <<= 1) {
        int u = __shfl_up(v, off, 64);
        if (lane >= off) v += u;
    }
    __syncthreads();
    if (lane == 63) scr[w] = v;
    __syncthreads();
    int base = 0;
    #pragma unroll
    for (int i = 0; i < 4; ++i) if (i < w) base += scr[i];
    return base + v - x;             // exclusive prefix
}

// ---------------- f16 accumulate helper ----------------
__device__ __forceinline__ void acc8(u4 x, f4& a0, f4& a1) {
    union { unsigned int u; __half2 h; } p0{x.x}, p1{x.y}, p2{x.z}, p3{x.w};
    a0.x += __low2float(p0.h); a0.y += __high2float(p0.h);
    a0.z += __low2float(p1.h); a0.w += __high2float(p1.h);
    a1.x += __low2float(p2.h); a1.y += __high2float(p2.h);
    a1.z += __low2float(p3.h); a1.w += __high2float(p3.h);
}

// ================= dispatch kernels =================

// ---- 1. convert k->f16 (blocks >= HB) + per-chunk bucket histogram (blocks < HB)
__global__ __launch_bounds__(256) void w_convhist(
    const int* __restrict__ A, int* __restrict__ bh, int E, int HB, int NB,
    const float* __restrict__ k, unsigned int* __restrict__ kh, int total8)
{
    __shared__ int h[256];
    int blk = blockIdx.x, t = threadIdx.x;
    if (blk >= HB) {                 // -------- convert part --------
        int i = (blk - HB) * 256 + t;
        if (i < total8) dev_convert(k, kh, i);
        return;
    }
    // -------- histogram part --------
    h[t] = 0;
    __syncthreads();
    int base = blk * EPB + t * 8;
    if (base + 8 <= E) {
        int4 a0 = *(const int4*)(A + base);
        int4 a1 = *(const int4*)(A + base + 4);
        atomicAdd(&h[a0.x >> 8], 1); atomicAdd(&h[a0.y >> 8], 1);
        atomicAdd(&h[a0.z >> 8], 1); atomicAdd(&h[a0.w >> 8], 1);
        atomicAdd(&h[a1.x >> 8], 1); atomicAdd(&h[a1.y >> 8], 1);
        atomicAdd(&h[a1.z >> 8], 1); atomicAdd(&h[a1.w >> 8], 1);
    } else {
        for (int j = 0; j < 8; ++j) { int i = base + j; if (i < E) atomicAdd(&h[A[i] >> 8], 1); }
    }
    __syncthreads();
    if (t < NB) bh[t * HB + blk] = h[t];   // bucket-major matrix
}

// ---- 2. per-bucket row sums (one block per bucket)
__global__ __launch_bounds__(256) void w_rowsum(const int* __restrict__ bh,
                                                int* __restrict__ rowsum, int HB) {
    __shared__ int scr[4];
    int g = blockIdx.x, t = threadIdx.x;
    int s = 0;
    for (int c = t; c < HB; c += 256) s += bh[g * HB + c];
    #pragma unroll
    for (int off = 32; off; off >>= 1) s += __shfl_down(s, off, 64);
    int lane = t & 63, w = t >> 6;
    if (lane == 0) scr[w] = s;
    __syncthreads();
    if (t == 0) rowsum[g] = scr[0] + scr[1] + scr[2] + scr[3];
}

// ---- 3. scan bucket bases (one tiny block over NB<=256 ints)
__global__ __launch_bounds__(256) void w_scanbase(const int* __restrict__ rowsum,
                                                  int* __restrict__ rowbase,
                                                  int* __restrict__ offsets,
                                                  int NB, int N, int E) {
    __shared__ int scr[4];
    int t = threadIdx.x;
    int x = (t < NB) ? rowsum[t] : 0;
    int p = excl_scan_256(x, t, scr);
    if (t <= NB) rowbase[t] = p;     // rowbase[NB] == E
    if (t == 0) offsets[N] = E;
}

// ---- 4. exclusive scan along each bucket row (one block per bucket)
__global__ __launch_bounds__(256) void w_rowscan(int* __restrict__ bh,
                                                 const int* __restrict__ rowbase, int HB) {
    __shared__ int scr[4];
    int g = blockIdx.x, t = threadIdx.x;
    int j0 = 2 * t, j1 = 2 * t + 1;
    int c0 = (j0 < HB) ? bh[g * HB + j0] : 0;
    int c1 = (j1 < HB) ? bh[g * HB + j1] : 0;
    int p = excl_scan_256(c0 + c1, t, scr);
    int base = rowbase[g];
    if (j0 < HB) bh[g * HB + j0] = base + p;
    if (j1 < HB) bh[g * HB + j1] = base + p + c0;
}

// ---- 5. scatter edges into bucket order (LDS cursors, no global atomics)
__global__ __launch_bounds__(256) void w_scatter(
    const int* __restrict__ A, const int* __restrict__ Bs, const int* __restrict__ bh,
    int* __restrict__ tmp, int E, int HB, int NB)
{
    __shared__ int cur[256];
    int blk = blockIdx.x, t = threadIdx.x;
    if (t < NB) cur[t] = bh[t * HB + blk];
    __syncthreads();
    int base = blk * EPB + t * 8;
    bool bal = ((((unsigned long long)(size_t)Bs) & 15) == 0);
    if (base + 8 <= E && bal) {
        int4 a0 = *(const int4*)(A + base);
        int4 a1 = *(const int4*)(A + base + 4);
        int4 b0 = *(const int4*)(Bs + base);
        int4 b1 = *(const int4*)(Bs + base + 4);
        int as[8] = {a0.x, a0.y, a0.z, a0.w, a1.x, a1.y, a1.z, a1.w};
        int bs[8] = {b0.x, b0.y, b0.z, b0.w, b1.x, b1.y, b1.z, b1.w};
        #pragma unroll
        for (int j = 0; j < 8; ++j) {
            int pos = atomicAdd(&cur[as[j] >> 8], 1);      // LDS atomic
            tmp[pos] = ((as[j] & 255) << 24) | bs[j];      // pack (A&255, B)
        }
    } else {
        for (int j = 0; j < 8; ++j) {
            int i = base + j;
            if (i < E) {
                int a = A[i], b = Bs[i];
                int pos = atomicAdd(&cur[a >> 8], 1);
                tmp[pos] = ((a & 255) << 24) | b;
            }
        }
    }
}

// ---- 6. per-bucket offsets + srcs (owner-computes, one block per bucket)
__global__ __launch_bounds__(256) void w_build(
    const int* __restrict__ rowbase, const int* __restrict__ tmp,
    int* __restrict__ offsets, int* __restrict__ srcs, int N, int E, int NB)
{
    __shared__ int cnt[256];
    __shared__ int scr[4];
    int g = blockIdx.x, t = threadIdx.x;
    int s = rowbase[g];
    int e = rowbase[g + 1];
    cnt[t] = 0;
    __syncthreads();
    for (int i = s + t; i < e; i += 256) atomicAdd(&cnt[(tmp[i] >> 24) & 255], 1);
    __syncthreads();
    int val = cnt[t];
    int p = excl_scan_256(val, t, scr);
    int n0 = (g << 8) + t;
    if (n0 < N) offsets[n0] = s + p;
    __syncthreads();
    cnt[t] = s + p;                  // reuse as cursor
    __syncthreads();
    for (int i = s + t; i < e; i += 256) {
        int wv = tmp[i];
        int pos = atomicAdd(&cnt[(wv >> 24) & 255], 1);   // LDS atomic
        srcs[pos] = wv & 0xFFFFFF;
    }
}

// ---- 7. node attention, f16 k (one wave per node), srcs-prefetch pipelined
__global__ __launch_bounds__(256) void w_node16(
    const float* __restrict__ q, const unsigned int* __restrict__ kh,
    const float* __restrict__ v, const int* __restrict__ offsets,
    const int* __restrict__ srcs, float* __restrict__ out, int N)
{
    __shared__ float lds[4][2 * 8 * LPAD + 64 + 8];
    int lane = threadIdx.x & 63;
    int wid  = threadIdx.x >> 6;
    int n = blockIdx.x * 4 + wid;
    bool active = n < N;

    float* qs = &lds[wid][0];
    float* ks = qs + 8 * LPAD;
    float* ps = ks + 8 * LPAD;

    int start = 0, end = 0;
    if (active) {
        start = __builtin_amdgcn_readfirstlane(offsets[n]);
        end   = __builtin_amdgcn_readfirstlane(offsets[n + 1]);
        int r0 = lane >> 4;
        int dq = (lane & 15) * 4;
        const f4* qn = (const f4*)(q + (size_t)n * ROW);
        f4 q0 = __builtin_nontemporal_load(qn + lane);
        f4 q1 = __builtin_nontemporal_load(qn + 64 + lane);
        *(f4*)(qs + r0 * LPAD + dq)       = q0;
        *(f4*)(qs + (r0 + 4) * LPAD + dq) = q1;
    }

    const u4* kh4 = (const u4*)kh;   // one u4 = 8 halves; one row = 64 u4
    f4 a0 = {0.f, 0.f, 0.f, 0.f}, a1 = {0.f, 0.f, 0.f, 0.f};
    int e = start;

    // software-pipelined 8-wide gather: indices for group i+1 are loaded
    // while group i's eight 16B k-row loads are in flight. acc8(x7) only
    // drains vmcnt to 8, so the prefetch stays outstanding through the
    // accumulate (vmcnt counts in issue order; srcs loads issued last).
    int b0, b1, b2, b3, b4, b5, b6, b7;
    if (e + 8 <= end) {
        b0 = srcs[e];     b1 = srcs[e + 1]; b2 = srcs[e + 2]; b3 = srcs[e + 3];
        b4 = srcs[e + 4]; b5 = srcs[e + 5]; b6 = srcs[e + 6]; b7 = srcs[e + 7];
    }
    while (e + 8 <= end) {
        u4 x0 = kh4[(size_t)b0 * 64 + lane];
        u4 x1 = kh4[(size_t)b1 * 64 + lane];
        u4 x2 = kh4[(size_t)b2 * 64 + lane];
        u4 x3 = kh4[(size_t)b3 * 64 + lane];
        u4 x4 = kh4[(size_t)b4 * 64 + lane];
        u4 x5 = kh4[(size_t)b5 * 64 + lane];
        u4 x6 = kh4[(size_t)b6 * 64 + lane];
        u4 x7 = kh4[(size_t)b7 * 64 + lane];
        e += 8;
        if (e + 8 <= end) {          // prefetch next group's indices
            b0 = srcs[e];     b1 = srcs[e + 1]; b2 = srcs[e + 2]; b3 = srcs[e + 3];
            b4 = srcs[e + 4]; b5 = srcs[e + 5]; b6 = srcs[e + 6]; b7 = srcs[e + 7];
        }
        acc8(x0, a0, a1); acc8(x1, a0, a1); acc8(x2, a0, a1); acc8(x3, a0, a1);
        acc8(x4, a0, a1); acc8(x5, a0, a1); acc8(x6, a0, a1); acc8(x7, a0, a1);
    }
    if (e + 4 <= end) {
        int c0 = srcs[e], c1 = srcs[e + 1], c2 = srcs[e + 2], c3 = srcs[e + 3];
        u4 x0 = kh4[(size_t)c0 * 64 + lane];
        u4 x1 = kh4[(size_t)c1 * 64 + lane];
        u4 x2 = kh4[(size_t)c2 * 64 + lane];
        u4 x3 = kh4[(size_t)c3 * 64 + lane];
        acc8(x0, a0, a1); acc8(x1, a0, a1); acc8(x2, a0, a1); acc8(x3, a0, a1);
        e += 4;
    }
    for (; e < end; ++e) {
        u4 x = kh4[(size_t)srcs[e] * 64 + lane];
        acc8(x, a0, a1);
    }

    if (active) {
        // lane holds Ksum flat elems [lane*8, lane*8+8): row g = lane>>3, d=(lane&7)*8+j
        int g = lane >> 3;
        int dbase = (lane & 7) * 8;
        *(f4*)(ks + g * LPAD + dbase)     = a0;
        *(f4*)(ks + g * LPAD + dbase + 4) = a1;
    }
    __syncthreads();

    if (active) {
        int h = lane >> 3, g = lane & 7;
        const f4* qrow = (const f4*)(qs + h * LPAD);
        const f4* krow = (const f4*)(ks + g * LPAD);
        float acc = 0.f;
        #pragma unroll
        for (int i = 0; i < 16; ++i) {
            f4 qa = qrow[i];
            f4 kb = krow[i];
            acc += qa.x * kb.x + qa.y * kb.y + qa.z * kb.z + qa.w * kb.w;
        }
        int cnt = end - start;
        float score = acc / (float)((cnt > 0) ? cnt : 1);
        float mx = score;
        #pragma unroll
        for (int off = 1; off < 8; off <<= 1)
            mx = fmaxf(mx, __shfl_xor(mx, off, 8));
        float ex = __expf(score - mx);
        float sm = ex;
        #pragma unroll
        for (int off = 1; off < 8; off <<= 1)
            sm += __shfl_xor(sm, off, 8);
        ps[h * 8 + g] = ex / sm;
    }
    __syncthreads();

    if (active) {
        int h0 = lane >> 4;
        int dbase = (lane & 15) * 4;
        const float* vb = v + (size_t)n * ROW;
        f4 o0 = {0.f, 0.f, 0.f, 0.f}, o1 = {0.f, 0.f, 0.f, 0.f};
        #pragma unroll
        for (int g = 0; g < 8; ++g) {
            f4 vg = __builtin_nontemporal_load((const f4*)(vb + g * 64 + dbase));
            float p0 = ps[h0 * 8 + g];
            float p1 = ps[(h0 + 4) * 8 + g];
            o0 += p0 * vg;
            o1 += p1 * vg;
        }
        f4* ob = (f4*)(out + (size_t)n * ROW);
        __builtin_nontemporal_store(o0, ob + lane);
        __builtin_nontemporal_store(o1, ob + 64 + lane);
    }
}

// ---- 7'. node attention, f32 k (fallback if workspace too small)
__global__ __launch_bounds__(256) void w_node32(
    const float* __restrict__ q, const float* __restrict__ k,
    const float* __restrict__ v, const int* __restrict__ offsets,
    const int* __restrict__ srcs, float* __restrict__ out, int N)
{
    __shared__ float lds[4][2 * 8 * LPAD + 64 + 8];
    int lane = threadIdx.x & 63;
    int wid  = threadIdx.x >> 6;
    int n = blockIdx.x * 4 + wid;
    bool active = n < N;

    float* qs = &lds[wid][0];
    float* ks = qs + 8 * LPAD;
    float* ps = ks + 8 * LPAD;

    int start = 0, end = 0;
    if (active) { start = offsets[n]; end = offsets[n + 1]; }

    f4 a0 = {0.f, 0.f, 0.f, 0.f}, a1 = {0.f, 0.f, 0.f, 0.f};
    for (int e = start; e < end; ++e) {
        int b = srcs[e];
        const f4* kb = (const f4*)(k + (size_t)b * ROW);
        f4 x0 = kb[lane];
        f4 x1 = kb[64 + lane];
        a0 += x0; a1 += x1;
    }

    if (active) {
        int r0 = lane >> 4;
        int dbase = (lane & 15) * 4;
        *(f4*)(ks + r0 * LPAD + dbase)       = a0;
        *(f4*)(ks + (r0 + 4) * LPAD + dbase) = a1;
        const f4* qn = (const f4*)(q + (size_t)n * ROW);
        f4 q0 = qn[lane], q1 = qn[64 + lane];
        *(f4*)(qs + r0 * LPAD + dbase)       = q0;
        *(f4*)(qs + (r0 + 4) * LPAD + dbase) = q1;
    }
    __syncthreads();

    if (active) {
        int h = lane >> 3, g = lane & 7;
        const f4* qrow = (const f4*)(qs + h * LPAD);
        const f4* krow = (const f4*)(ks + g * LPAD);
        float acc = 0.f;
        #pragma unroll
        for (int i = 0; i < 16; ++i) {
            f4 qa = qrow[i];
            f4 kb = krow[i];
            acc += qa.x * kb.x + qa.y * kb.y + qa.z * kb.z + qa.w * kb.w;
        }
        int cnt = end - start;
        float score = acc / (float)((cnt > 0) ? cnt : 1);
        float mx = score;
        #pragma unroll
        for (int off = 1; off < 8; off <<= 1)
            mx = fmaxf(mx, __shfl_xor(mx, off, 8));
        float ex = __expf(score - mx);
        float sm = ex;
        #pragma unroll
        for (int off = 1; off < 8; off <<= 1)
            sm += __shfl_xor(sm, off, 8);
        ps[h * 8 + g] = ex / sm;
    }
    __syncthreads();

    if (active) {
        int h0 = lane >> 4;
        int dbase = (lane & 15) * 4;
        const float* vb = v + (size_t)n * ROW;
        f4 o0 = {0.f, 0.f, 0.f, 0.f}, o1 = {0.f, 0.f, 0.f, 0.f};
        #pragma unroll
        for (int g = 0; g < 8; ++g) {
            f4 vg = *(const f4*)(vb + g * 64 + dbase);
            float p0 = ps[h0 * 8 + g];
            float p1 = ps[(h0 + 4) * 8 + g];
            o0 += p0 * vg;
            o1 += p1 * vg;
        }
        f4* ob = (f4*)(out + (size_t)n * ROW);
        ob[lane]      = o0;
        ob[64 + lane] = o1;
    }
}

// ================= host launcher =================
extern "C" void kernel_launch(void* const* d_in, const int* in_sizes, int n_in,
                              void* d_out, int out_size, void* d_ws, size_t ws_size,
                              hipStream_t stream) {
    const float* q  = (const float*)d_in[0];
    const float* k  = (const float*)d_in[1];
    const float* v  = (const float*)d_in[2];
    const int*   ei = (const int*)d_in[3];

    int N = in_sizes[0] / ROW;
    int E = in_sizes[3] / 2;
    const int* A  = ei;
    const int* Bs = ei + E;

    int HB = (E + EPB - 1) / EPB;       // edge chunks (391)
    int NB = (N + 255) >> 8;            // node buckets (196) -- requires N <= 65536

    // workspace layout (ints), then kh (f16 k) 256B-aligned
    int* offsets = (int*)d_ws;                       // N+1
    int* srcs    = offsets + (N + 1);                // E
    int* tmp     = srcs + E;                         // E
    int* bh      = tmp + E;                          // NB*HB
    int* rowsum  = bh + (size_t)NB * HB;             // NB
    int* rowbase = rowsum + NB;                      // NB+1
    size_t int_words = (size_t)(N + 1) + 2 * (size_t)E + (size_t)NB * HB + NB + (NB + 1);
    size_t kh_off = ((int_words * 4 + 255) & ~(size_t)255);
    unsigned int* kh = (unsigned int*)((char*)d_ws + kh_off);
    bool use_f16 = ws_size >= kh_off + (size_t)N * ROW * 2;
    int total8 = N * (ROW / 8);
    int CONVB  = (total8 + 255) / 256;
    float* out = (float*)d_out;

    w_convhist<<<HB + (use_f16 ? CONVB : 0), 256, 0, stream>>>(A, bh, E, HB, NB, k, kh, total8);
    w_rowsum<<<NB, 256, 0, stream>>>(bh, rowsum, HB);
    w_scanbase<<<1, 256, 0, stream>>>(rowsum, rowbase, offsets, NB, N, E);
    w_rowscan<<<NB, 256, 0, stream>>>(bh, rowbase, HB);
    w_scatter<<<HB, 256, 0, stream>>>(A, Bs, bh, tmp, E, HB, NB);
    w_build<<<NB, 256, 0, stream>>>(rowbase, tmp, offsets, srcs, N, E, NB);
    if (use_f16)
        w_node16<<<(N + 3) / 4, 256, 0, stream>>>(q, kh, v, offsets, srcs, out, N);
    else
        w_node32<<<(N + 3) / 4, 256, 0, stream>>>(q, k, v, offsets, srcs, out, N);
}

// Round 7
// 381.381 us; speedup vs baseline: 1.1573x; 1.1165x over previous
//
#include <hip/hip_runtime.h>
#include <hip/hip_fp16.h>

// Graph scaled-dot-product attention, N=50000, E=800000, H=8, D=64.
// seg_sum[n] = Q[n] @ (sum_{e:A_e=n} K[B_e])^T -- only Ksum needed per node.
//
// Round-7: R6 structure verbatim + ONE change: k gathered as per-(node,head)
// scaled INT8 (8B/lane) instead of f16 (16B/lane). Evidence: node kernel is
// pinned at ~3.8 TB/s across all structural variants (occupancy 52->70% null,
// index prefetch null) => pure byte wall; k is the only multi-use operand
// (16x reuse), so halving its gather bytes is the only remaining lever.
// Quant err std ~0.007/elem -> output absmax predicted ~0.05 vs ~0.097 tol.

#define ROW 512          // H*D floats per node
#define LPAD 68          // padded LDS row stride (floats)
#define EPB 2048         // edges per hist/scatter chunk (256 thr * 8)

typedef float f4 __attribute__((ext_vector_type(4)));
typedef unsigned int u4 __attribute__((ext_vector_type(4)));

// ================= device helpers =================

// per-node int8 quantization: one wave per node. Lane holds flat elems
// [lane*8, lane*8+8) = head g = lane>>3, so an 8-lane group spans one
// 64-elem head row; group-max -> scale s = max/127.
__device__ __forceinline__ void dev_quant(const float* __restrict__ k,
                                          unsigned int* __restrict__ kb8,
                                          float* __restrict__ scl,
                                          int n, int lane) {
    const f4* src = (const f4*)(k + (size_t)n * ROW);
    f4 x0 = __builtin_nontemporal_load(src + lane * 2);      // k f32 read once
    f4 x1 = __builtin_nontemporal_load(src + lane * 2 + 1);
    float m = fmaxf(fmaxf(fmaxf(fabsf(x0.x), fabsf(x0.y)), fmaxf(fabsf(x0.z), fabsf(x0.w))),
                    fmaxf(fmaxf(fabsf(x1.x), fabsf(x1.y)), fmaxf(fabsf(x1.z), fabsf(x1.w))));
    #pragma unroll
    for (int off = 1; off < 8; off <<= 1)
        m = fmaxf(m, __shfl_xor(m, off, 8));                 // max over head row
    float inv = (m > 0.f) ? 127.0f / m : 0.f;
    int r0 = (int)rintf(x0.x * inv), r1 = (int)rintf(x0.y * inv);
    int r2 = (int)rintf(x0.z * inv), r3 = (int)rintf(x0.w * inv);
    int r4 = (int)rintf(x1.x * inv), r5 = (int)rintf(x1.y * inv);
    int r6 = (int)rintf(x1.z * inv), r7 = (int)rintf(x1.w * inv);
    unsigned lo = (unsigned)(r0 & 255) | ((unsigned)(r1 & 255) << 8) |
                  ((unsigned)(r2 & 255) << 16) | ((unsigned)(r3 & 255) << 24);
    unsigned hi = (unsigned)(r4 & 255) | ((unsigned)(r5 & 255) << 8) |
                  ((unsigned)(r6 & 255) << 16) | ((unsigned)(r7 & 255) << 24);
    uint2 w; w.x = lo; w.y = hi;
    ((uint2*)kb8)[(size_t)n * 64 + lane] = w;                // row = 64 uint2 = 512 B
    if ((lane & 7) == 0) scl[n * 8 + (lane >> 3)] = m * (1.0f / 127.0f);
}

// int8 dequant-accumulate: 8 elems from one uint2 + head scale s
__device__ __forceinline__ void acci8(uint2 w, float s, f4& a0, f4& a1) {
    int lo = (int)w.x, hi = (int)w.y;
    a0.x += s * (float)(char)(lo);
    a0.y += s * (float)(char)(lo >> 8);
    a0.z += s * (float)(char)(lo >> 16);
    a0.w += s * (float)(lo >> 24);
    a1.x += s * (float)(char)(hi);
    a1.y += s * (float)(char)(hi >> 8);
    a1.z += s * (float)(char)(hi >> 16);
    a1.w += s * (float)(hi >> 24);
}

// block-wide exclusive scan over 256 ints (needs scr[4]+)
__device__ __forceinline__ int excl_scan_256(int x, int t, int* scr) {
    int lane = t & 63, w = t >> 6;
    int v = x;
    #pragma unroll
    for (int off = 1; off < 64; off <<= 1) {
        int u = __shfl_up(v, off, 64);
        if (lane >= off) v += u;
    }
    __syncthreads();
    if (lane == 63) scr[w] = v;
    __syncthreads();
    int base = 0;
    #pragma unroll
    for (int i = 0; i < 4; ++i) if (i < w) base += scr[i];
    return base + v - x;             // exclusive prefix
}

// ================= dispatch kernels =================

// ---- 1. quantize k->int8 (blocks >= HB, 4 nodes/block) + bucket histogram
__global__ __launch_bounds__(256) void w_quanthist(
    const int* __restrict__ A, int* __restrict__ bh, int E, int HB, int NB,
    const float* __restrict__ k, unsigned int* __restrict__ kb8,
    float* __restrict__ scl, int N)
{
    __shared__ int h[256];
    int blk = blockIdx.x, t = threadIdx.x;
    if (blk >= HB) {                 // -------- quant part --------
        int nb = (blk - HB) * 4 + (t >> 6);
        if (nb < N) dev_quant(k, kb8, scl, nb, t & 63);
        return;
    }
    // -------- histogram part --------
    h[t] = 0;
    __syncthreads();
    int base = blk * EPB + t * 8;
    if (base + 8 <= E) {
        int4 a0 = *(const int4*)(A + base);
        int4 a1 = *(const int4*)(A + base + 4);
        atomicAdd(&h[a0.x >> 8], 1); atomicAdd(&h[a0.y >> 8], 1);
        atomicAdd(&h[a0.z >> 8], 1); atomicAdd(&h[a0.w >> 8], 1);
        atomicAdd(&h[a1.x >> 8], 1); atomicAdd(&h[a1.y >> 8], 1);
        atomicAdd(&h[a1.z >> 8], 1); atomicAdd(&h[a1.w >> 8], 1);
    } else {
        for (int j = 0; j < 8; ++j) { int i = base + j; if (i < E) atomicAdd(&h[A[i] >> 8], 1); }
    }
    __syncthreads();
    if (t < NB) bh[t * HB + blk] = h[t];   // bucket-major matrix
}

// ---- 2. per-bucket row sums (one block per bucket)
__global__ __launch_bounds__(256) void w_rowsum(const int* __restrict__ bh,
                                                int* __restrict__ rowsum, int HB) {
    __shared__ int scr[4];
    int g = blockIdx.x, t = threadIdx.x;
    int s = 0;
    for (int c = t; c < HB; c += 256) s += bh[g * HB + c];
    #pragma unroll
    for (int off = 32; off; off >>= 1) s += __shfl_down(s, off, 64);
    int lane = t & 63, w = t >> 6;
    if (lane == 0) scr[w] = s;
    __syncthreads();
    if (t == 0) rowsum[g] = scr[0] + scr[1] + scr[2] + scr[3];
}

// ---- 3. scan bucket bases (one tiny block over NB<=256 ints)
__global__ __launch_bounds__(256) void w_scanbase(const int* __restrict__ rowsum,
                                                  int* __restrict__ rowbase,
                                                  int* __restrict__ offsets,
                                                  int NB, int N, int E) {
    __shared__ int scr[4];
    int t = threadIdx.x;
    int x = (t < NB) ? rowsum[t] : 0;
    int p = excl_scan_256(x, t, scr);
    if (t <= NB) rowbase[t] = p;     // rowbase[NB] == E
    if (t == 0) offsets[N] = E;
}

// ---- 4. exclusive scan along each bucket row (one block per bucket)
__global__ __launch_bounds__(256) void w_rowscan(int* __restrict__ bh,
                                                 const int* __restrict__ rowbase, int HB) {
    __shared__ int scr[4];
    int g = blockIdx.x, t = threadIdx.x;
    int j0 = 2 * t, j1 = 2 * t + 1;
    int c0 = (j0 < HB) ? bh[g * HB + j0] : 0;
    int c1 = (j1 < HB) ? bh[g * HB + j1] : 0;
    int p = excl_scan_256(c0 + c1, t, scr);
    int base = rowbase[g];
    if (j0 < HB) bh[g * HB + j0] = base + p;
    if (j1 < HB) bh[g * HB + j1] = base + p + c0;
}

// ---- 5. scatter edges into bucket order (LDS cursors, no global atomics)
__global__ __launch_bounds__(256) void w_scatter(
    const int* __restrict__ A, const int* __restrict__ Bs, const int* __restrict__ bh,
    int* __restrict__ tmp, int E, int HB, int NB)
{
    __shared__ int cur[256];
    int blk = blockIdx.x, t = threadIdx.x;
    if (t < NB) cur[t] = bh[t * HB + blk];
    __syncthreads();
    int base = blk * EPB + t * 8;
    bool bal = ((((unsigned long long)(size_t)Bs) & 15) == 0);
    if (base + 8 <= E && bal) {
        int4 a0 = *(const int4*)(A + base);
        int4 a1 = *(const int4*)(A + base + 4);
        int4 b0 = *(const int4*)(Bs + base);
        int4 b1 = *(const int4*)(Bs + base + 4);
        int as[8] = {a0.x, a0.y, a0.z, a0.w, a1.x, a1.y, a1.z, a1.w};
        int bs[8] = {b0.x, b0.y, b0.z, b0.w, b1.x, b1.y, b1.z, b1.w};
        #pragma unroll
        for (int j = 0; j < 8; ++j) {
            int pos = atomicAdd(&cur[as[j] >> 8], 1);      // LDS atomic
            tmp[pos] = ((as[j] & 255) << 24) | bs[j];      // pack (A&255, B)
        }
    } else {
        for (int j = 0; j < 8; ++j) {
            int i = base + j;
            if (i < E) {
                int a = A[i], b = Bs[i];
                int pos = atomicAdd(&cur[a >> 8], 1);
                tmp[pos] = ((a & 255) << 24) | b;
            }
        }
    }
}

// ---- 6. per-bucket offsets + srcs (owner-computes, one block per bucket)
__global__ __launch_bounds__(256) void w_build(
    const int* __restrict__ rowbase, const int* __restrict__ tmp,
    int* __restrict__ offsets, int* __restrict__ srcs, int N, int E, int NB)
{
    __shared__ int cnt[256];
    __shared__ int scr[4];
    int g = blockIdx.x, t = threadIdx.x;
    int s = rowbase[g];
    int e = rowbase[g + 1];
    cnt[t] = 0;
    __syncthreads();
    for (int i = s + t; i < e; i += 256) atomicAdd(&cnt[(tmp[i] >> 24) & 255], 1);
    __syncthreads();
    int val = cnt[t];
    int p = excl_scan_256(val, t, scr);
    int n0 = (g << 8) + t;
    if (n0 < N) offsets[n0] = s + p;
    __syncthreads();
    cnt[t] = s + p;                  // reuse as cursor
    __syncthreads();
    for (int i = s + t; i < e; i += 256) {
        int wv = tmp[i];
        int pos = atomicAdd(&cnt[(wv >> 24) & 255], 1);   // LDS atomic
        srcs[pos] = wv & 0xFFFFFF;
    }
}

// ---- 7. node attention, int8 k (one wave per node), srcs-prefetch pipelined
__global__ __launch_bounds__(256) void w_node8(
    const float* __restrict__ q, const unsigned int* __restrict__ kb8,
    const float* __restrict__ scl, const float* __restrict__ v,
    const int* __restrict__ offsets, const int* __restrict__ srcs,
    float* __restrict__ out, int N)
{
    __shared__ float lds[4][2 * 8 * LPAD + 64 + 8];
    int lane = threadIdx.x & 63;
    int wid  = threadIdx.x >> 6;
    int n = blockIdx.x * 4 + wid;
    bool active = n < N;
    int g8 = lane >> 3;              // head index of this lane's 8 elems

    float* qs = &lds[wid][0];
    float* ks = qs + 8 * LPAD;
    float* ps = ks + 8 * LPAD;

    int start = 0, end = 0;
    if (active) {
        start = __builtin_amdgcn_readfirstlane(offsets[n]);
        end   = __builtin_amdgcn_readfirstlane(offsets[n + 1]);
        int r0 = lane >> 4;
        int dq = (lane & 15) * 4;
        const f4* qn = (const f4*)(q + (size_t)n * ROW);
        f4 q0 = __builtin_nontemporal_load(qn + lane);
        f4 q1 = __builtin_nontemporal_load(qn + 64 + lane);
        *(f4*)(qs + r0 * LPAD + dq)       = q0;
        *(f4*)(qs + (r0 + 4) * LPAD + dq) = q1;
    }

    const uint2* kr = (const uint2*)kb8;   // one uint2 = 8 int8; one row = 64 uint2
    f4 a0 = {0.f, 0.f, 0.f, 0.f}, a1 = {0.f, 0.f, 0.f, 0.f};
    int e = start;

    int b0, b1, b2, b3, b4, b5, b6, b7;
    if (e + 8 <= end) {
        b0 = srcs[e];     b1 = srcs[e + 1]; b2 = srcs[e + 2]; b3 = srcs[e + 3];
        b4 = srcs[e + 4]; b5 = srcs[e + 5]; b6 = srcs[e + 6]; b7 = srcs[e + 7];
    }
    while (e + 8 <= end) {
        uint2 x0 = kr[(size_t)b0 * 64 + lane];
        uint2 x1 = kr[(size_t)b1 * 64 + lane];
        uint2 x2 = kr[(size_t)b2 * 64 + lane];
        uint2 x3 = kr[(size_t)b3 * 64 + lane];
        uint2 x4 = kr[(size_t)b4 * 64 + lane];
        uint2 x5 = kr[(size_t)b5 * 64 + lane];
        uint2 x6 = kr[(size_t)b6 * 64 + lane];
        uint2 x7 = kr[(size_t)b7 * 64 + lane];
        float s0 = scl[b0 * 8 + g8], s1 = scl[b1 * 8 + g8];
        float s2 = scl[b2 * 8 + g8], s3 = scl[b3 * 8 + g8];
        float s4 = scl[b4 * 8 + g8], s5 = scl[b5 * 8 + g8];
        float s6 = scl[b6 * 8 + g8], s7 = scl[b7 * 8 + g8];
        e += 8;
        if (e + 8 <= end) {          // prefetch next group's indices
            b0 = srcs[e];     b1 = srcs[e + 1]; b2 = srcs[e + 2]; b3 = srcs[e + 3];
            b4 = srcs[e + 4]; b5 = srcs[e + 5]; b6 = srcs[e + 6]; b7 = srcs[e + 7];
        }
        acci8(x0, s0, a0, a1); acci8(x1, s1, a0, a1);
        acci8(x2, s2, a0, a1); acci8(x3, s3, a0, a1);
        acci8(x4, s4, a0, a1); acci8(x5, s5, a0, a1);
        acci8(x6, s6, a0, a1); acci8(x7, s7, a0, a1);
    }
    if (e + 4 <= end) {
        int c0 = srcs[e], c1 = srcs[e + 1], c2 = srcs[e + 2], c3 = srcs[e + 3];
        uint2 x0 = kr[(size_t)c0 * 64 + lane];
        uint2 x1 = kr[(size_t)c1 * 64 + lane];
        uint2 x2 = kr[(size_t)c2 * 64 + lane];
        uint2 x3 = kr[(size_t)c3 * 64 + lane];
        float s0 = scl[c0 * 8 + g8], s1 = scl[c1 * 8 + g8];
        float s2 = scl[c2 * 8 + g8], s3 = scl[c3 * 8 + g8];
        acci8(x0, s0, a0, a1); acci8(x1, s1, a0, a1);
        acci8(x2, s2, a0, a1); acci8(x3, s3, a0, a1);
        e += 4;
    }
    for (; e < end; ++e) {
        int b = srcs[e];
        uint2 x = kr[(size_t)b * 64 + lane];
        float s = scl[b * 8 + g8];
        acci8(x, s, a0, a1);
    }

    if (active) {
        // lane holds Ksum flat elems [lane*8, lane*8+8): row g = lane>>3, d=(lane&7)*8+j
        int g = lane >> 3;
        int dbase = (lane & 7) * 8;
        *(f4*)(ks + g * LPAD + dbase)     = a0;
        *(f4*)(ks + g * LPAD + dbase + 4) = a1;
    }
    __syncthreads();

    if (active) {
        int h = lane >> 3, g = lane & 7;
        const f4* qrow = (const f4*)(qs + h * LPAD);
        const f4* krow = (const f4*)(ks + g * LPAD);
        float acc = 0.f;
        #pragma unroll
        for (int i = 0; i < 16; ++i) {
            f4 qa = qrow[i];
            f4 kb = krow[i];
            acc += qa.x * kb.x + qa.y * kb.y + qa.z * kb.z + qa.w * kb.w;
        }
        int cnt = end - start;
        float score = acc / (float)((cnt > 0) ? cnt : 1);
        float mx = score;
        #pragma unroll
        for (int off = 1; off < 8; off <<= 1)
            mx = fmaxf(mx, __shfl_xor(mx, off, 8));
        float ex = __expf(score - mx);
        float sm = ex;
        #pragma unroll
        for (int off = 1; off < 8; off <<= 1)
            sm += __shfl_xor(sm, off, 8);
        ps[h * 8 + g] = ex / sm;
    }
    __syncthreads();

    if (active) {
        int h0 = lane >> 4;
        int dbase = (lane & 15) * 4;
        const float* vb = v + (size_t)n * ROW;
        f4 o0 = {0.f, 0.f, 0.f, 0.f}, o1 = {0.f, 0.f, 0.f, 0.f};
        #pragma unroll
        for (int g = 0; g < 8; ++g) {
            f4 vg = __builtin_nontemporal_load((const f4*)(vb + g * 64 + dbase));
            float p0 = ps[h0 * 8 + g];
            float p1 = ps[(h0 + 4) * 8 + g];
            o0 += p0 * vg;
            o1 += p1 * vg;
        }
        f4* ob = (f4*)(out + (size_t)n * ROW);
        __builtin_nontemporal_store(o0, ob + lane);
        __builtin_nontemporal_store(o1, ob + 64 + lane);
    }
}

// ---- 7'. node attention, f32 k (fallback if workspace too small)
__global__ __launch_bounds__(256) void w_node32(
    const float* __restrict__ q, const float* __restrict__ k,
    const float* __restrict__ v, const int* __restrict__ offsets,
    const int* __restrict__ srcs, float* __restrict__ out, int N)
{
    __shared__ float lds[4][2 * 8 * LPAD + 64 + 8];
    int lane = threadIdx.x & 63;
    int wid  = threadIdx.x >> 6;
    int n = blockIdx.x * 4 + wid;
    bool active = n < N;

    float* qs = &lds[wid][0];
    float* ks = qs + 8 * LPAD;
    float* ps = ks + 8 * LPAD;

    int start = 0, end = 0;
    if (active) { start = offsets[n]; end = offsets[n + 1]; }

    f4 a0 = {0.f, 0.f, 0.f, 0.f}, a1 = {0.f, 0.f, 0.f, 0.f};
    for (int e = start; e < end; ++e) {
        int b = srcs[e];
        const f4* kb = (const f4*)(k + (size_t)b * ROW);
        f4 x0 = kb[lane];
        f4 x1 = kb[64 + lane];
        a0 += x0; a1 += x1;
    }

    if (active) {
        int r0 = lane >> 4;
        int dbase = (lane & 15) * 4;
        *(f4*)(ks + r0 * LPAD + dbase)       = a0;
        *(f4*)(ks + (r0 + 4) * LPAD + dbase) = a1;
        const f4* qn = (const f4*)(q + (size_t)n * ROW);
        f4 q0 = qn[lane], q1 = qn[64 + lane];
        *(f4*)(qs + r0 * LPAD + dbase)       = q0;
        *(f4*)(qs + (r0 + 4) * LPAD + dbase) = q1;
    }
    __syncthreads();

    if (active) {
        int h = lane >> 3, g = lane & 7;
        const f4* qrow = (const f4*)(qs + h * LPAD);
        const f4* krow = (const f4*)(ks + g * LPAD);
        float acc = 0.f;
        #pragma unroll
        for (int i = 0; i < 16; ++i) {
            f4 qa = qrow[i];
            f4 kb = krow[i];
            acc += qa.x * kb.x + qa.y * kb.y + qa.z * kb.z + qa.w * kb.w;
        }
        int cnt = end - start;
        float score = acc / (float)((cnt > 0) ? cnt : 1);
        float mx = score;
        #pragma unroll
        for (int off = 1; off < 8; off <<= 1)
            mx = fmaxf(mx, __shfl_xor(mx, off, 8));
        float ex = __expf(score - mx);
        float sm = ex;
        #pragma unroll
        for (int off = 1; off < 8; off <<= 1)
            sm += __shfl_xor(sm, off, 8);
        ps[h * 8 + g] = ex / sm;
    }
    __syncthreads();

    if (active) {
        int h0 = lane >> 4;
        int dbase = (lane & 15) * 4;
        const float* vb = v + (size_t)n * ROW;
        f4 o0 = {0.f, 0.f, 0.f, 0.f}, o1 = {0.f, 0.f, 0.f, 0.f};
        #pragma unroll
        for (int g = 0; g < 8; ++g) {
            f4 vg = *(const f4*)(vb + g * 64 + dbase);
            float p0 = ps[h0 * 8 + g];
            float p1 = ps[(h0 + 4) * 8 + g];
            o0 += p0 * vg;
            o1 += p1 * vg;
        }
        f4* ob = (f4*)(out + (size_t)n * ROW);
        ob[lane]      = o0;
        ob[64 + lane] = o1;
    }
}

// ================= host launcher =================
extern "C" void kernel_launch(void* const* d_in, const int* in_sizes, int n_in,
                              void* d_out, int out_size, void* d_ws, size_t ws_size,
                              hipStream_t stream) {
    const float* q  = (const float*)d_in[0];
    const float* k  = (const float*)d_in[1];
    const float* v  = (const float*)d_in[2];
    const int*   ei = (const int*)d_in[3];

    int N = in_sizes[0] / ROW;
    int E = in_sizes[3] / 2;
    const int* A  = ei;
    const int* Bs = ei + E;

    int HB = (E + EPB - 1) / EPB;       // edge chunks (391)
    int NB = (N + 255) >> 8;            // node buckets (196) -- requires N <= 65536

    // workspace layout (ints), then scl (N*8 f32), then kb8 (N*512 B) 256B-al
    int* offsets = (int*)d_ws;                       // N+1
    int* srcs    = offsets + (N + 1);                // E
    int* tmp     = srcs + E;                         // E
    int* bh      = tmp + E;                          // NB*HB
    int* rowsum  = bh + (size_t)NB * HB;             // NB
    int* rowbase = rowsum + NB;                      // NB+1
    float* scl   = (float*)(rowbase + NB + 1);       // N*8
    size_t int_words = (size_t)(N + 1) + 2 * (size_t)E + (size_t)NB * HB + NB + (NB + 1)
                     + (size_t)N * 8;
    size_t kb8_off = ((int_words * 4 + 255) & ~(size_t)255);
    unsigned int* kb8 = (unsigned int*)((char*)d_ws + kb8_off);
    bool use_i8 = ws_size >= kb8_off + (size_t)N * 512;
    int QUANTB = (N + 3) / 4;
    float* out = (float*)d_out;

    w_quanthist<<<HB + (use_i8 ? QUANTB : 0), 256, 0, stream>>>(
        A, bh, E, HB, NB, k, kb8, scl, use_i8 ? N : 0);
    w_rowsum<<<NB, 256, 0, stream>>>(bh, rowsum, HB);
    w_scanbase<<<1, 256, 0, stream>>>(rowsum, rowbase, offsets, NB, N, E);
    w_rowscan<<<NB, 256, 0, stream>>>(bh, rowbase, HB);
    w_scatter<<<HB, 256, 0, stream>>>(A, Bs, bh, tmp, E, HB, NB);
    w_build<<<NB, 256, 0, stream>>>(rowbase, tmp, offsets, srcs, N, E, NB);
    if (use_i8)
        w_node8<<<(N + 3) / 4, 256, 0, stream>>>(q, kb8, scl, v, offsets, srcs, out, N);
    else
        w_node32<<<(N + 3) / 4, 256, 0, stream>>>(q, k, v, offsets, srcs, out, N);
}

// Round 8
// 376.371 us; speedup vs baseline: 1.1727x; 1.0133x over previous
//
#include <hip/hip_runtime.h>
#include <hip/hip_fp16.h>

// Graph scaled-dot-product attention, N=50000, E=800000, H=8, D=64.
// seg_sum[n] = Q[n] @ (sum_{e:A_e=n} K[B_e])^T -- only Ksum needed per node.
// k gathered as per-(node,head) scaled int8 (verified R7: absmax 0.0937, pass).
//
// Round-8: prep collapsed to {memset, quant+scatter, build} via fixed-capacity
// bucket regions (5120 slots/bucket, 16-sigma slack). Kills hist + 3 scan
// dispatches (~25-30us of the ~57us prep). Scatter reserves space with one
// global atomicAdd per (block,bucket) (~38k atomics); build emits starts/ends
// per node (no dense CSR -> no global scan). Node kernel = R7 verbatim
// (111us, pinned at the measured ~3.8 TB/s mixed-traffic wall), reading
// starts/ends instead of offsets. Quantizer untouched -> absmax unchanged.

#define ROW 512          // H*D floats per node
#define LPAD 68          // padded LDS row stride (floats)
#define SEPB 4096        // edges per scatter block (256 thr * 16)
#define CAPB 5120        // slots per bucket region (expected 4082, sigma 64)

typedef float f4 __attribute__((ext_vector_type(4)));
typedef unsigned int u4 __attribute__((ext_vector_type(4)));

// ================= device helpers =================

// per-node int8 quantization: one wave per node. Lane holds flat elems
// [lane*8, lane*8+8) = head g = lane>>3; 8-lane group spans one 64-elem head
// row; group-max -> scale s = max/127.  (UNCHANGED from R7 -- absmax-critical.)
__device__ __forceinline__ void dev_quant(const float* __restrict__ k,
                                          unsigned int* __restrict__ kb8,
                                          float* __restrict__ scl,
                                          int n, int lane) {
    const f4* src = (const f4*)(k + (size_t)n * ROW);
    f4 x0 = __builtin_nontemporal_load(src + lane * 2);      // k f32 read once
    f4 x1 = __builtin_nontemporal_load(src + lane * 2 + 1);
    float m = fmaxf(fmaxf(fmaxf(fabsf(x0.x), fabsf(x0.y)), fmaxf(fabsf(x0.z), fabsf(x0.w))),
                    fmaxf(fmaxf(fabsf(x1.x), fabsf(x1.y)), fmaxf(fabsf(x1.z), fabsf(x1.w))));
    #pragma unroll
    for (int off = 1; off < 8; off <<= 1)
        m = fmaxf(m, __shfl_xor(m, off, 8));                 // max over head row
    float inv = (m > 0.f) ? 127.0f / m : 0.f;
    int r0 = (int)rintf(x0.x * inv), r1 = (int)rintf(x0.y * inv);
    int r2 = (int)rintf(x0.z * inv), r3 = (int)rintf(x0.w * inv);
    int r4 = (int)rintf(x1.x * inv), r5 = (int)rintf(x1.y * inv);
    int r6 = (int)rintf(x1.z * inv), r7 = (int)rintf(x1.w * inv);
    unsigned lo = (unsigned)(r0 & 255) | ((unsigned)(r1 & 255) << 8) |
                  ((unsigned)(r2 & 255) << 16) | ((unsigned)(r3 & 255) << 24);
    unsigned hi = (unsigned)(r4 & 255) | ((unsigned)(r5 & 255) << 8) |
                  ((unsigned)(r6 & 255) << 16) | ((unsigned)(r7 & 255) << 24);
    uint2 w; w.x = lo; w.y = hi;
    ((uint2*)kb8)[(size_t)n * 64 + lane] = w;                // row = 64 uint2 = 512 B
    if ((lane & 7) == 0) scl[n * 8 + (lane >> 3)] = m * (1.0f / 127.0f);
}

// int8 dequant-accumulate: 8 elems from one uint2 + head scale s
__device__ __forceinline__ void acci8(uint2 w, float s, f4& a0, f4& a1) {
    int lo = (int)w.x, hi = (int)w.y;
    a0.x += s * (float)(char)(lo);
    a0.y += s * (float)(char)(lo >> 8);
    a0.z += s * (float)(char)(lo >> 16);
    a0.w += s * (float)(lo >> 24);
    a1.x += s * (float)(char)(hi);
    a1.y += s * (float)(char)(hi >> 8);
    a1.z += s * (float)(char)(hi >> 16);
    a1.w += s * (float)(hi >> 24);
}

// block-wide exclusive scan over 256 ints (needs scr[4]+)
__device__ __forceinline__ int excl_scan_256(int x, int t, int* scr) {
    int lane = t & 63, w = t >> 6;
    int v = x;
    #pragma unroll
    for (int off = 1; off < 64; off <<= 1) {
        int u = __shfl_up(v, off, 64);
        if (lane >= off) v += u;
    }
    __syncthreads();
    if (lane == 63) scr[w] = v;
    __syncthreads();
    int base = 0;
    #pragma unroll
    for (int i = 0; i < 4; ++i) if (i < w) base += scr[i];
    return base + v - x;             // exclusive prefix
}

// ================= dispatch kernels =================

// ---- 1. fused: quantize k->int8 (blocks >= SB) + bucket scatter (blocks < SB)
// Scatter: LDS count per bucket -> one global atomicAdd per (block,bucket) to
// reserve a range in the bucket's fixed region -> place edges via LDS cursors.
__global__ __launch_bounds__(256) void w_quantscat(
    const int* __restrict__ A, const int* __restrict__ Bs,
    int* __restrict__ relCur, int* __restrict__ tmp, int E, int SB, int NB,
    const float* __restrict__ k, unsigned int* __restrict__ kb8,
    float* __restrict__ scl, int N)
{
    __shared__ int cnt[256];
    __shared__ int rbase[256];
    int blk = blockIdx.x, t = threadIdx.x;
    if (blk >= SB) {                 // -------- quant part --------
        int nb = (blk - SB) * 4 + (t >> 6);
        if (nb < N) dev_quant(k, kb8, scl, nb, t & 63);
        return;
    }
    // -------- scatter part --------
    cnt[t] = 0;
    __syncthreads();
    int ebase = blk * SEPB + t * 16;
    bool bal = ((((unsigned long long)(size_t)Bs) & 15) == 0);
    // pass 1: count this block's edges per bucket
    if (ebase + 16 <= E) {
        #pragma unroll
        for (int c = 0; c < 4; ++c) {
            int4 a = *(const int4*)(A + ebase + c * 4);
            atomicAdd(&cnt[a.x >> 8], 1); atomicAdd(&cnt[a.y >> 8], 1);
            atomicAdd(&cnt[a.z >> 8], 1); atomicAdd(&cnt[a.w >> 8], 1);
        }
    } else {
        for (int j = 0; j < 16; ++j) { int i = ebase + j; if (i < E) atomicAdd(&cnt[A[i] >> 8], 1); }
    }
    __syncthreads();
    // reserve contiguous range in each touched bucket's region
    if (t < NB) {
        int c = cnt[t];
        rbase[t] = (c > 0) ? atomicAdd(&relCur[t], c) : 0;   // device-scope, ~38k total
    }
    __syncthreads();
    cnt[t] = 0;                      // reuse as local cursor
    __syncthreads();
    // pass 2: place edges
    if (ebase + 16 <= E && bal) {
        #pragma unroll
        for (int c = 0; c < 4; ++c) {
            int4 a = *(const int4*)(A + ebase + c * 4);
            int4 b = *(const int4*)(Bs + ebase + c * 4);
            int as[4] = {a.x, a.y, a.z, a.w};
            int bs[4] = {b.x, b.y, b.z, b.w};
            #pragma unroll
            for (int j = 0; j < 4; ++j) {
                int g = as[j] >> 8;
                int p = atomicAdd(&cnt[g], 1);               // LDS atomic
                int pos = rbase[g] + p;
                if (pos < CAPB)
                    tmp[g * CAPB + pos] = ((as[j] & 255) << 24) | bs[j];
            }
        }
    } else {
        for (int j = 0; j < 16; ++j) {
            int i = ebase + j;
            if (i < E) {
                int a = A[i], b = Bs[i], g = a >> 8;
                int p = atomicAdd(&cnt[g], 1);
                int pos = rbase[g] + p;
                if (pos < CAPB)
                    tmp[g * CAPB + pos] = ((a & 255) << 24) | b;
            }
        }
    }
}

// ---- 2. per-bucket build: starts/ends + node-sorted srcs (owner-computes)
__global__ __launch_bounds__(256) void w_build(
    const int* __restrict__ relCur, const int* __restrict__ tmp,
    int* __restrict__ starts, int* __restrict__ ends, int* __restrict__ srcs,
    int N, int NB)
{
    __shared__ int cnt[256];
    __shared__ int scr[4];
    int g = blockIdx.x, t = threadIdx.x;
    int total = relCur[g];
    if (total > CAPB) total = CAPB;
    int s = g * CAPB;
    cnt[t] = 0;
    __syncthreads();
    for (int i = t; i < total; i += 256) atomicAdd(&cnt[(tmp[s + i] >> 24) & 255], 1);
    __syncthreads();
    int val = cnt[t];
    int p = excl_scan_256(val, t, scr);
    int n0 = (g << 8) + t;
    if (n0 < N) { starts[n0] = s + p; ends[n0] = s + p + val; }
    __syncthreads();
    cnt[t] = s + p;                  // reuse as cursor
    __syncthreads();
    for (int i = t; i < total; i += 256) {
        int wv = tmp[s + i];
        int pos = atomicAdd(&cnt[(wv >> 24) & 255], 1);      // LDS atomic
        srcs[pos] = wv & 0xFFFFFF;
    }
}

// ---- 3. node attention, int8 k (one wave per node) -- R7 verbatim, starts/ends
__global__ __launch_bounds__(256) void w_node8(
    const float* __restrict__ q, const unsigned int* __restrict__ kb8,
    const float* __restrict__ scl, const float* __restrict__ v,
    const int* __restrict__ starts, const int* __restrict__ ends,
    const int* __restrict__ srcs, float* __restrict__ out, int N)
{
    __shared__ float lds[4][2 * 8 * LPAD + 64 + 8];
    int lane = threadIdx.x & 63;
    int wid  = threadIdx.x >> 6;
    int n = blockIdx.x * 4 + wid;
    bool active = n < N;
    int g8 = lane >> 3;              // head index of this lane's 8 elems

    float* qs = &lds[wid][0];
    float* ks = qs + 8 * LPAD;
    float* ps = ks + 8 * LPAD;

    int start = 0, end = 0;
    if (active) {
        start = __builtin_amdgcn_readfirstlane(starts[n]);
        end   = __builtin_amdgcn_readfirstlane(ends[n]);
        int r0 = lane >> 4;
        int dq = (lane & 15) * 4;
        const f4* qn = (const f4*)(q + (size_t)n * ROW);
        f4 q0 = __builtin_nontemporal_load(qn + lane);
        f4 q1 = __builtin_nontemporal_load(qn + 64 + lane);
        *(f4*)(qs + r0 * LPAD + dq)       = q0;
        *(f4*)(qs + (r0 + 4) * LPAD + dq) = q1;
    }

    const uint2* kr = (const uint2*)kb8;   // one uint2 = 8 int8; one row = 64 uint2
    f4 a0 = {0.f, 0.f, 0.f, 0.f}, a1 = {0.f, 0.f, 0.f, 0.f};
    int e = start;

    int b0, b1, b2, b3, b4, b5, b6, b7;
    if (e + 8 <= end) {
        b0 = srcs[e];     b1 = srcs[e + 1]; b2 = srcs[e + 2]; b3 = srcs[e + 3];
        b4 = srcs[e + 4]; b5 = srcs[e + 5]; b6 = srcs[e + 6]; b7 = srcs[e + 7];
    }
    while (e + 8 <= end) {
        uint2 x0 = kr[(size_t)b0 * 64 + lane];
        uint2 x1 = kr[(size_t)b1 * 64 + lane];
        uint2 x2 = kr[(size_t)b2 * 64 + lane];
        uint2 x3 = kr[(size_t)b3 * 64 + lane];
        uint2 x4 = kr[(size_t)b4 * 64 + lane];
        uint2 x5 = kr[(size_t)b5 * 64 + lane];
        uint2 x6 = kr[(size_t)b6 * 64 + lane];
        uint2 x7 = kr[(size_t)b7 * 64 + lane];
        float s0 = scl[b0 * 8 + g8], s1 = scl[b1 * 8 + g8];
        float s2 = scl[b2 * 8 + g8], s3 = scl[b3 * 8 + g8];
        float s4 = scl[b4 * 8 + g8], s5 = scl[b5 * 8 + g8];
        float s6 = scl[b6 * 8 + g8], s7 = scl[b7 * 8 + g8];
        e += 8;
        if (e + 8 <= end) {          // prefetch next group's indices
            b0 = srcs[e];     b1 = srcs[e + 1]; b2 = srcs[e + 2]; b3 = srcs[e + 3];
            b4 = srcs[e + 4]; b5 = srcs[e + 5]; b6 = srcs[e + 6]; b7 = srcs[e + 7];
        }
        acci8(x0, s0, a0, a1); acci8(x1, s1, a0, a1);
        acci8(x2, s2, a0, a1); acci8(x3, s3, a0, a1);
        acci8(x4, s4, a0, a1); acci8(x5, s5, a0, a1);
        acci8(x6, s6, a0, a1); acci8(x7, s7, a0, a1);
    }
    if (e + 4 <= end) {
        int c0 = srcs[e], c1 = srcs[e + 1], c2 = srcs[e + 2], c3 = srcs[e + 3];
        uint2 x0 = kr[(size_t)c0 * 64 + lane];
        uint2 x1 = kr[(size_t)c1 * 64 + lane];
        uint2 x2 = kr[(size_t)c2 * 64 + lane];
        uint2 x3 = kr[(size_t)c3 * 64 + lane];
        float s0 = scl[c0 * 8 + g8], s1 = scl[c1 * 8 + g8];
        float s2 = scl[c2 * 8 + g8], s3 = scl[c3 * 8 + g8];
        acci8(x0, s0, a0, a1); acci8(x1, s1, a0, a1);
        acci8(x2, s2, a0, a1); acci8(x3, s3, a0, a1);
        e += 4;
    }
    for (; e < end; ++e) {
        int b = srcs[e];
        uint2 x = kr[(size_t)b * 64 + lane];
        float s = scl[b * 8 + g8];
        acci8(x, s, a0, a1);
    }

    if (active) {
        // lane holds Ksum flat elems [lane*8, lane*8+8): row g = lane>>3, d=(lane&7)*8+j
        int g = lane >> 3;
        int dbase = (lane & 7) * 8;
        *(f4*)(ks + g * LPAD + dbase)     = a0;
        *(f4*)(ks + g * LPAD + dbase + 4) = a1;
    }
    __syncthreads();

    if (active) {
        int h = lane >> 3, g = lane & 7;
        const f4* qrow = (const f4*)(qs + h * LPAD);
        const f4* krow = (const f4*)(ks + g * LPAD);
        float acc = 0.f;
        #pragma unroll
        for (int i = 0; i < 16; ++i) {
            f4 qa = qrow[i];
            f4 kb = krow[i];
            acc += qa.x * kb.x + qa.y * kb.y + qa.z * kb.z + qa.w * kb.w;
        }
        int cnt = end - start;
        float score = acc / (float)((cnt > 0) ? cnt : 1);
        float mx = score;
        #pragma unroll
        for (int off = 1; off < 8; off <<= 1)
            mx = fmaxf(mx, __shfl_xor(mx, off, 8));
        float ex = __expf(score - mx);
        float sm = ex;
        #pragma unroll
        for (int off = 1; off < 8; off <<= 1)
            sm += __shfl_xor(sm, off, 8);
        ps[h * 8 + g] = ex / sm;
    }
    __syncthreads();

    if (active) {
        int h0 = lane >> 4;
        int dbase = (lane & 15) * 4;
        const float* vb = v + (size_t)n * ROW;
        f4 o0 = {0.f, 0.f, 0.f, 0.f}, o1 = {0.f, 0.f, 0.f, 0.f};
        #pragma unroll
        for (int g = 0; g < 8; ++g) {
            f4 vg = __builtin_nontemporal_load((const f4*)(vb + g * 64 + dbase));
            float p0 = ps[h0 * 8 + g];
            float p1 = ps[(h0 + 4) * 8 + g];
            o0 += p0 * vg;
            o1 += p1 * vg;
        }
        f4* ob = (f4*)(out + (size_t)n * ROW);
        __builtin_nontemporal_store(o0, ob + lane);
        __builtin_nontemporal_store(o1, ob + 64 + lane);
    }
}

// ---- 3'. node attention, f32 k (fallback if workspace too small for kb8)
__global__ __launch_bounds__(256) void w_node32(
    const float* __restrict__ q, const float* __restrict__ k,
    const float* __restrict__ v, const int* __restrict__ starts,
    const int* __restrict__ ends, const int* __restrict__ srcs,
    float* __restrict__ out, int N)
{
    __shared__ float lds[4][2 * 8 * LPAD + 64 + 8];
    int lane = threadIdx.x & 63;
    int wid  = threadIdx.x >> 6;
    int n = blockIdx.x * 4 + wid;
    bool active = n < N;

    float* qs = &lds[wid][0];
    float* ks = qs + 8 * LPAD;
    float* ps = ks + 8 * LPAD;

    int start = 0, end = 0;
    if (active) { start = starts[n]; end = ends[n]; }

    f4 a0 = {0.f, 0.f, 0.f, 0.f}, a1 = {0.f, 0.f, 0.f, 0.f};
    for (int e = start; e < end; ++e) {
        int b = srcs[e];
        const f4* kb = (const f4*)(k + (size_t)b * ROW);
        f4 x0 = kb[lane];
        f4 x1 = kb[64 + lane];
        a0 += x0; a1 += x1;
    }

    if (active) {
        int r0 = lane >> 4;
        int dbase = (lane & 15) * 4;
        *(f4*)(ks + r0 * LPAD + dbase)       = a0;
        *(f4*)(ks + (r0 + 4) * LPAD + dbase) = a1;
        const f4* qn = (const f4*)(q + (size_t)n * ROW);
        f4 q0 = qn[lane], q1 = qn[64 + lane];
        *(f4*)(qs + r0 * LPAD + dbase)       = q0;
        *(f4*)(qs + (r0 + 4) * LPAD + dbase) = q1;
    }
    __syncthreads();

    if (active) {
        int h = lane >> 3, g = lane & 7;
        const f4* qrow = (const f4*)(qs + h * LPAD);
        const f4* krow = (const f4*)(ks + g * LPAD);
        float acc = 0.f;
        #pragma unroll
        for (int i = 0; i < 16; ++i) {
            f4 qa = qrow[i];
            f4 kb = krow[i];
            acc += qa.x * kb.x + qa.y * kb.y + qa.z * kb.z + qa.w * kb.w;
        }
        int cnt = end - start;
        float score = acc / (float)((cnt > 0) ? cnt : 1);
        float mx = score;
        #pragma unroll
        for (int off = 1; off < 8; off <<= 1)
            mx = fmaxf(mx, __shfl_xor(mx, off, 8));
        float ex = __expf(score - mx);
        float sm = ex;
        #pragma unroll
        for (int off = 1; off < 8; off <<= 1)
            sm += __shfl_xor(sm, off, 8);
        ps[h * 8 + g] = ex / sm;
    }
    __syncthreads();

    if (active) {
        int h0 = lane >> 4;
        int dbase = (lane & 15) * 4;
        const float* vb = v + (size_t)n * ROW;
        f4 o0 = {0.f, 0.f, 0.f, 0.f}, o1 = {0.f, 0.f, 0.f, 0.f};
        #pragma unroll
        for (int g = 0; g < 8; ++g) {
            f4 vg = *(const f4*)(vb + g * 64 + dbase);
            float p0 = ps[h0 * 8 + g];
            float p1 = ps[(h0 + 4) * 8 + g];
            o0 += p0 * vg;
            o1 += p1 * vg;
        }
        f4* ob = (f4*)(out + (size_t)n * ROW);
        ob[lane]      = o0;
        ob[64 + lane] = o1;
    }
}

// ================= host launcher =================
extern "C" void kernel_launch(void* const* d_in, const int* in_sizes, int n_in,
                              void* d_out, int out_size, void* d_ws, size_t ws_size,
                              hipStream_t stream) {
    const float* q  = (const float*)d_in[0];
    const float* k  = (const float*)d_in[1];
    const float* v  = (const float*)d_in[2];
    const int*   ei = (const int*)d_in[3];

    int N = in_sizes[0] / ROW;
    int E = in_sizes[3] / 2;
    const int* A  = ei;
    const int* Bs = ei + E;

    int SB = (E + SEPB - 1) / SEPB;     // scatter blocks (196)
    int NB = (N + 255) >> 8;            // node buckets (196) -- requires N <= 65536

    // workspace: starts[N] ends[N] relCur[NB] | tmp[NB*CAPB] srcs[NB*CAPB]
    //            scl[N*8] | kb8 (N*512 B), 256B-aligned
    int* starts = (int*)d_ws;                        // N
    int* ends   = starts + N;                        // N
    int* relCur = ends + N;                          // NB
    int* tmp    = relCur + NB;                       // NB*CAPB
    int* srcs   = tmp + (size_t)NB * CAPB;           // NB*CAPB
    float* scl  = (float*)(srcs + (size_t)NB * CAPB);// N*8
    size_t int_words = 2 * (size_t)N + NB + 2 * (size_t)NB * CAPB + (size_t)N * 8;
    size_t kb8_off = ((int_words * 4 + 255) & ~(size_t)255);
    unsigned int* kb8 = (unsigned int*)((char*)d_ws + kb8_off);
    bool use_i8 = ws_size >= kb8_off + (size_t)N * 512;
    int QUANTB = (N + 3) / 4;
    float* out = (float*)d_out;

    hipMemsetAsync(relCur, 0, (size_t)NB * sizeof(int), stream);
    w_quantscat<<<SB + (use_i8 ? QUANTB : 0), 256, 0, stream>>>(
        A, Bs, relCur, tmp, E, SB, NB, k, kb8, scl, use_i8 ? N : 0);
    w_build<<<NB, 256, 0, stream>>>(relCur, tmp, starts, ends, srcs, N, NB);
    if (use_i8)
        w_node8<<<(N + 3) / 4, 256, 0, stream>>>(q, kb8, scl, v, starts, ends, srcs, out, N);
    else
        w_node32<<<(N + 3) / 4, 256, 0, stream>>>(q, k, v, starts, ends, srcs, out, N);
}